// Round 3
// baseline (1828.973 us; speedup 1.0000x reference)
//
#include <hip/hip_runtime.h>
#include <hip/hip_bf16.h>

// Problem constants (match reference)
#define NN   50000   // N0+N1
#define NN0  30000
#define EE   400000

typedef unsigned short u16;
typedef unsigned int   u32;

// ---------- bf16 storage helpers (fp32 math everywhere) ----------
__device__ __forceinline__ float bf2f(u16 u){ return __uint_as_float(((u32)u)<<16); }
__device__ __forceinline__ float lo16(u32 u){ return __uint_as_float(u<<16); }
__device__ __forceinline__ float hi16(u32 u){ return __uint_as_float(u & 0xffff0000u); }
__device__ __forceinline__ u16 f2bf(float f){
  u32 x = __float_as_uint(f);
  x += 0x7fffu + ((x>>16)&1u);      // round-to-nearest-even
  return (u16)(x>>16);
}
__device__ __forceinline__ float elu_f(float x){ return x>0.f ? x : __expf(x)-1.f; }
__device__ __forceinline__ float lrelu(float x){ return x>0.f ? x : 0.2f*x; }

// ---------- f32 -> bf16 weight conversion ----------
__global__ void k_f2b(const float* __restrict__ in, u16* __restrict__ out, int n){
  int t = blockIdx.x*256 + threadIdx.x;
  if (t < n) out[t] = f2bf(in[t]);
}

// ---------- mix_w softmax over graphs: w[(type*3+l)*2+i] ----------
__global__ void k_mixw(const float* __restrict__ mix_w, float* __restrict__ wsoft){
  int t = threadIdx.x;
  if (t < 6){
    float a0 = mix_w[t*2+0];
    float a1 = mix_w[t*2+1];
    float mx = fmaxf(a0,a1);
    float e0 = __expf(a0-mx), e1 = __expf(a1-mx);
    float s = e0+e1;
    wsoft[t*2+0] = e0/s; wsoft[t*2+1] = e1/s;
  }
}

// ================= CSR build (per graph, rebuilt every launch) =================
__global__ void k_count(const int* __restrict__ dst, int* __restrict__ cnt){
  int t = blockIdx.x*256 + threadIdx.x;
  if (t < EE) atomicAdd(&cnt[dst[t]], 1);
}

// exclusive scan of cnt[0..NN-1] -> row[0..NN], single 1024-thread block
__global__ __launch_bounds__(1024) void k_scan(const int* __restrict__ cnt, int* __restrict__ row){
  __shared__ int wsum[16];
  __shared__ int base;
  if (threadIdx.x == 0) base = 0;
  __syncthreads();
  int lane = threadIdx.x & 63, wid = threadIdx.x >> 6;
  for (int start = 0; start < NN; start += 1024){
    int i = start + threadIdx.x;
    int v = (i < NN) ? cnt[i] : 0;
    int x = v;
    #pragma unroll
    for (int off = 1; off < 64; off <<= 1){
      int y = __shfl_up(x, off, 64);
      if (lane >= off) x += y;
    }
    if (lane == 63) wsum[wid] = x;
    __syncthreads();
    if (wid == 0 && lane < 16){
      int s = wsum[lane];
      #pragma unroll
      for (int off = 1; off < 16; off <<= 1){
        int y = __shfl_up(s, off, 16);
        if (lane >= off) s += y;
      }
      wsum[lane] = s;
    }
    __syncthreads();
    int incl = x + (wid ? wsum[wid-1] : 0) + base;
    if (i < NN) row[i] = incl - v;     // exclusive
    __syncthreads();
    if (threadIdx.x == 1023) base = incl;
    __syncthreads();
  }
  if (threadIdx.x == 0) row[NN] = base;   // == EE
}

__global__ void k_scatter(const int* __restrict__ src, const int* __restrict__ dst,
                          const int* __restrict__ row, int* __restrict__ fill,
                          int* __restrict__ col){
  int t = blockIdx.x*256 + threadIdx.x;
  if (t >= EE) return;
  int d = dst[t];
  int pos = atomicAdd(&fill[d], 1);
  col[row[d] + pos] = src[t];
}

// ---------- input projection: h(N,64) = feat_t @ fc_w_t + fc_b_t (f32 in, bf16 out)
__global__ __launch_bounds__(256) void k_in_proj(
    const float* __restrict__ f0, const float* __restrict__ f1,
    const float* __restrict__ w0, const float* __restrict__ b0,
    const float* __restrict__ w1, const float* __restrict__ b1,
    u16* __restrict__ h)
{
  __shared__ float fs[4][128];
  int wv = threadIdx.x>>6, ln = threadIdx.x&63;
  int n = blockIdx.x*4 + wv;                // N divisible by 4
  const float *fr, *W, *B;
  if (n < NN0){ fr = f0 + (size_t)n*128; W=w0; B=b0; }
  else        { fr = f1 + (size_t)(n-NN0)*128; W=w1; B=b1; }
  float2 u = ((const float2*)fr)[ln];
  fs[wv][2*ln]   = u.x;
  fs[wv][2*ln+1] = u.y;
  __syncthreads();
  float acc = B[ln];
  #pragma unroll 8
  for (int k=0;k<128;k++) acc = fmaf(fs[wv][k], W[k*64+ln], acc);
  h[(size_t)n*64 + ln] = f2bf(acc);
}

// ---------- feat = h @ W (K x 256), fused el/er epilogue ----------
// one wave per node; lane handles 4 consecutive output cols. W is bf16 (uint2/lane).
template<int K>
__global__ __launch_bounds__(256) void k_feat(
    const u16* __restrict__ hin, const u16* __restrict__ Wb,
    const float* __restrict__ al, const float* __restrict__ ar,
    u16* __restrict__ feat, float* __restrict__ el, float* __restrict__ er)
{
  __shared__ u16 hs[4][256];
  int wv = threadIdx.x>>6, ln = threadIdx.x&63;
  int n = blockIdx.x*4 + wv;
  for (int k=ln; k<K; k+=64) hs[wv][k] = hin[(size_t)n*K + k];
  __syncthreads();
  const uint2* Wp = (const uint2*)Wb;       // 4 bf16 per lane per k
  float a0=0.f,a1=0.f,a2=0.f,a3=0.f;
  #pragma unroll 4
  for (int k=0;k<K;k++){
    float hv = bf2f(hs[wv][k]);
    uint2 w = Wp[(size_t)k*64 + ln];
    a0 = fmaf(hv, lo16(w.x), a0);
    a1 = fmaf(hv, hi16(w.x), a1);
    a2 = fmaf(hv, lo16(w.y), a2);
    a3 = fmaf(hv, hi16(w.y), a3);
  }
  float4 av = ((const float4*)al)[ln];      // al[h*64+d], flat index 4*ln
  float4 rv = ((const float4*)ar)[ln];
  float ep = a0*av.x + a1*av.y + a2*av.z + a3*av.w;
  float rp = a0*rv.x + a1*rv.y + a2*rv.z + a3*rv.w;
  for (int off=8; off; off>>=1){ ep += __shfl_xor(ep,off,16); rp += __shfl_xor(rp,off,16); }
  if ((ln&15)==0){ int hd = ln>>4; el[n*4+hd]=ep; er[n*4+hd]=rp; }
  uint2 o;
  o.x = (u32)f2bf(a0) | ((u32)f2bf(a1)<<16);
  o.y = (u32)f2bf(a2) | ((u32)f2bf(a3)<<16);
  ((uint2*)feat)[(size_t)n*64 + ln] = o;
}

// ---------- gather aggregation, layers 0/1 (256 cols, H=4) ----------
// one wave per node; lane = 4 contiguous cols; head = lane>>4.
// two passes over incoming edges: online softmax (m, den), then weighted gather.
template<int RES>
__global__ __launch_bounds__(256) void k_aggN(
    const int* __restrict__ row, const int* __restrict__ col,
    const u16* __restrict__ feat, const float* __restrict__ el, const float* __restrict__ er,
    const u16* __restrict__ hres, const float* __restrict__ bias,
    const float* __restrict__ wsoft, int l, int i, int first,
    u16* __restrict__ hout)
{
  int wv = threadIdx.x>>6, ln = threadIdx.x&63;
  int n = blockIdx.x*4 + wv;
  int h = ln>>4;
  int beg = row[n], end = row[n+1];
  float er_h = er[n*4+h];
  float m = -1e30f, den = 0.f;
  for (int k=beg; k<end; k++){
    int s = col[k];
    float e = lrelu(el[s*4+h] + er_h);
    float mn = fmaxf(m, e);
    den = den*__expf(m-mn) + __expf(e-mn);
    m = mn;
  }
  float inv = (end>beg) ? 1.0f/den : 0.f;
  float a0=0.f,a1=0.f,a2=0.f,a3=0.f;
  for (int k=beg; k<end; k++){
    int s = col[k];
    float e = lrelu(el[s*4+h] + er_h);
    float a = __expf(e-m)*inv;
    uint2 f = ((const uint2*)feat)[(size_t)s*64 + ln];
    a0 = fmaf(a, lo16(f.x), a0);
    a1 = fmaf(a, hi16(f.x), a1);
    a2 = fmaf(a, lo16(f.y), a2);
    a3 = fmaf(a, hi16(f.y), a3);
  }
  float4 bv = ((const float4*)bias)[ln];
  a0 += bv.x; a1 += bv.y; a2 += bv.z; a3 += bv.w;
  if (RES){
    uint2 r = ((const uint2*)hres)[(size_t)n*64 + ln];
    a0 += lo16(r.x); a1 += hi16(r.x); a2 += lo16(r.y); a3 += hi16(r.y);
  }
  a0 = elu_f(a0); a1 = elu_f(a1); a2 = elu_f(a2); a3 = elu_f(a3);
  float w = wsoft[((n<NN0)?0:1)*6 + l*2 + i];
  a0 *= w; a1 *= w; a2 *= w; a3 *= w;
  if (!first){
    uint2 p = ((const uint2*)hout)[(size_t)n*64 + ln];
    a0 += lo16(p.x); a1 += hi16(p.x); a2 += lo16(p.y); a3 += hi16(p.y);
  }
  uint2 o;
  o.x = (u32)f2bf(a0) | ((u32)f2bf(a1)<<16);
  o.y = (u32)f2bf(a2) | ((u32)f2bf(a3)<<16);
  ((uint2*)hout)[(size_t)n*64 + ln] = o;
}

// ---------- layer-2 GEMM (256 -> 16) + el/er epilogue ----------
__global__ __launch_bounds__(256) void k_feat16(
    const u16* __restrict__ hin, const u16* __restrict__ Wb,
    const float* __restrict__ al, const float* __restrict__ ar,
    float* __restrict__ feat16, float* __restrict__ el, float* __restrict__ er)
{
  __shared__ u16 hs[16*256];
  int t = threadIdx.x;
  const uint2* g = (const uint2*)(hin + (size_t)blockIdx.x*16*256);
  uint2* hs2 = (uint2*)hs;
  #pragma unroll
  for (int q=0;q<4;q++) hs2[t + q*256] = g[t + q*256];
  __syncthreads();
  int nl = t>>4, j = t&15;
  int n = blockIdx.x*16 + nl;
  const u16* hr = hs + nl*256;
  float acc=0.f;
  #pragma unroll 8
  for (int k=0;k<256;k++) acc = fmaf(bf2f(hr[k]), bf2f(Wb[k*16+j]), acc);
  float ep = acc*al[j];
  float rp = acc*ar[j];
  for (int off=8; off; off>>=1){ ep += __shfl_xor(ep,off,16); rp += __shfl_xor(rp,off,16); }
  if (j==0){ el[n]=ep; er[n]=rp; }
  feat16[(size_t)n*16+j] = acc;
}

// ---------- layer-2 fc residual: resb = h @ res2 (f32, no bias) ----------
__global__ __launch_bounds__(256) void k_res16(
    const u16* __restrict__ hin, const u16* __restrict__ Rb, float* __restrict__ resb)
{
  __shared__ u16 hs[16*256];
  int t = threadIdx.x;
  const uint2* g = (const uint2*)(hin + (size_t)blockIdx.x*16*256);
  uint2* hs2 = (uint2*)hs;
  #pragma unroll
  for (int q=0;q<4;q++) hs2[t + q*256] = g[t + q*256];
  __syncthreads();
  int nl = t>>4, j = t&15;
  int n = blockIdx.x*16 + nl;
  const u16* hr = hs + nl*256;
  float acc = 0.f;
  #pragma unroll 8
  for (int k=0;k<256;k++) acc = fmaf(bf2f(hr[k]), bf2f(Rb[k*16+j]), acc);
  resb[(size_t)n*16+j] = acc;
}

// ---------- layer-2 gather aggregation (16 cols, H=1) + final mix (f32 out) ----
__global__ __launch_bounds__(256) void k_agg2(
    const int* __restrict__ row, const int* __restrict__ col,
    const float* __restrict__ feat16, const float* __restrict__ el, const float* __restrict__ er,
    const float* __restrict__ resb, const float* __restrict__ b2,
    const float* __restrict__ wsoft, int i, int first, float* __restrict__ out)
{
  int t = threadIdx.x;
  int nl = t>>4, j = t&15;
  int n = blockIdx.x*16 + nl;
  int beg = row[n], end = row[n+1];
  float ern = er[n];
  float m = -1e30f, den = 0.f;
  for (int k=beg; k<end; k++){
    float e = lrelu(el[col[k]] + ern);
    float mn = fmaxf(m, e);
    den = den*__expf(m-mn) + __expf(e-mn);
    m = mn;
  }
  float inv = (end>beg) ? 1.0f/den : 0.f;
  float acc = 0.f;
  for (int k=beg; k<end; k++){
    int s = col[k];
    float e = lrelu(el[s] + ern);
    acc = fmaf(__expf(e-m)*inv, feat16[(size_t)s*16+j], acc);
  }
  float o = acc + b2[j] + resb[(size_t)n*16+j];
  float w = wsoft[((n<NN0)?0:1)*6 + 4 + i];
  float r = o*w;
  if (!first) r += out[(size_t)n*16+j];
  out[(size_t)n*16+j] = r;
}

extern "C" void kernel_launch(void* const* d_in, const int* in_sizes, int n_in,
                              void* d_out, int out_size, void* d_ws, size_t ws_size,
                              hipStream_t stream)
{
  const float* features0 = (const float*)d_in[0];
  const float* features1 = (const float*)d_in[1];
  const float* fc_w0 = (const float*)d_in[2];
  const float* fc_b0 = (const float*)d_in[3];
  const float* fc_w1 = (const float*)d_in[4];
  const float* fc_b1 = (const float*)d_in[5];
  const float* mix_w = (const float*)d_in[6];
  const float* W0  = (const float*)d_in[7];
  const float* al0 = (const float*)d_in[8];
  const float* ar0 = (const float*)d_in[9];
  const float* b0  = (const float*)d_in[10];
  const float* W1  = (const float*)d_in[11];
  const float* al1 = (const float*)d_in[12];
  const float* ar1 = (const float*)d_in[13];
  const float* b1  = (const float*)d_in[14];
  const float* W2  = (const float*)d_in[15];
  const float* al2 = (const float*)d_in[16];
  const float* ar2 = (const float*)d_in[17];
  const float* b2  = (const float*)d_in[18];
  const float* res2= (const float*)d_in[19];
  const int* src[2] = {(const int*)d_in[20], (const int*)d_in[22]};
  const int* dst[2] = {(const int*)d_in[21], (const int*)d_in[23]};
  (void)in_sizes; (void)n_in; (void)out_size; (void)ws_size;

  // workspace layout (~90 MB)
  char* ws = (char*)d_ws;
  size_t off = 0;
  auto alloc = [&](size_t bytes)->char*{
    char* p = ws + off; off += (bytes + 255) & ~(size_t)255; return p;
  };
  float* wsoft = (float*)alloc(64*4);
  u16*   hA    = (u16*)  alloc((size_t)NN*256*2);
  u16*   hB    = (u16*)  alloc((size_t)NN*256*2);
  u16*   feat  = (u16*)  alloc((size_t)NN*256*2);
  float* el    = (float*)alloc((size_t)NN*4*4);
  float* er    = (float*)alloc((size_t)NN*4*4);
  float* resb  = (float*)alloc((size_t)NN*16*4);
  float* feat16= (float*)alloc((size_t)NN*16*4);
  u16*   W0b   = (u16*)  alloc((size_t)2*64*256*2);
  u16*   W1b   = (u16*)  alloc((size_t)2*256*256*2);
  u16*   W2b   = (u16*)  alloc((size_t)2*256*16*2);
  u16*   R2b   = (u16*)  alloc((size_t)2*256*16*2);
  int*   rowg[2]; int* colg[2];
  rowg[0] = (int*)alloc((size_t)(NN+1)*4);
  colg[0] = (int*)alloc((size_t)EE*4);
  rowg[1] = (int*)alloc((size_t)(NN+1)*4);
  colg[1] = (int*)alloc((size_t)EE*4);
  int*   cnt   = (int*)alloc((size_t)NN*4);
  int*   fill  = (int*)alloc((size_t)NN*4);

  k_mixw<<<1,64,0,stream>>>(mix_w, wsoft);

  // convert GEMM weights to bf16 (halves the broadcast weight stream)
  k_f2b<<<(2*64*256+255)/256,256,0,stream>>>(W0,  W0b, 2*64*256);
  k_f2b<<<(2*256*256+255)/256,256,0,stream>>>(W1, W1b, 2*256*256);
  k_f2b<<<(2*256*16+255)/256,256,0,stream>>>(W2,  W2b, 2*256*16);
  k_f2b<<<(2*256*16+255)/256,256,0,stream>>>(res2,R2b, 2*256*16);

  // Build CSR (dst-sorted adjacency) per graph — int atomics only
  for (int g=0; g<2; g++){
    hipMemsetAsync(cnt,  0, (size_t)NN*4, stream);
    hipMemsetAsync(fill, 0, (size_t)NN*4, stream);
    k_count  <<<(EE+255)/256,256,0,stream>>>(dst[g], cnt);
    k_scan   <<<1,1024,0,stream>>>(cnt, rowg[g]);
    k_scatter<<<(EE+255)/256,256,0,stream>>>(src[g], dst[g], rowg[g], fill, colg[g]);
  }

  k_in_proj<<<NN/4,256,0,stream>>>(features0, features1, fc_w0, fc_b0, fc_w1, fc_b1, hA);

  // layer 0: h (N,64) -> hB (N,256); no residual
  for (int i=0; i<2; i++){
    k_feat<64><<<NN/4,256,0,stream>>>(hA, W0b+(size_t)i*64*256, al0+i*256, ar0+i*256, feat, el, er);
    k_aggN<0><<<NN/4,256,0,stream>>>(rowg[i], colg[i], feat, el, er,
                                     (const u16*)nullptr, b0+i*256, wsoft, 0, i, (i==0)?1:0, hB);
  }
  // layer 1: hB (N,256) -> hA (N,256); identity residual
  for (int i=0; i<2; i++){
    k_feat<256><<<NN/4,256,0,stream>>>(hB, W1b+(size_t)i*256*256, al1+i*256, ar1+i*256, feat, el, er);
    k_aggN<1><<<NN/4,256,0,stream>>>(rowg[i], colg[i], feat, el, er,
                                     hB, b1+i*256, wsoft, 1, i, (i==0)?1:0, hA);
  }
  // layer 2: hA (N,256) -> logits (N,16); fc residual, no activation
  for (int i=0; i<2; i++){
    k_feat16<<<NN/16,256,0,stream>>>(hA, W2b+(size_t)i*256*16, al2+i*16, ar2+i*16, feat16, el, er);
    k_res16 <<<NN/16,256,0,stream>>>(hA, R2b+(size_t)i*256*16, resb);
    k_agg2  <<<NN/16,256,0,stream>>>(rowg[i], colg[i], feat16, el, er, resb, b2+i*16,
                                     wsoft, i, (i==0)?1:0, (float*)d_out);
  }
}

// Round 4
// 1093.407 us; speedup vs baseline: 1.6727x; 1.6727x over previous
//
#include <hip/hip_runtime.h>
#include <hip/hip_bf16.h>

// Problem constants (match reference)
#define NN   50000   // N0+N1
#define NN0  30000
#define EE   400000

typedef unsigned short u16;
typedef unsigned int   u32;

typedef __attribute__((ext_vector_type(8))) __bf16 bf16x8;
typedef __attribute__((ext_vector_type(4))) float  f32x4;

// ---------- bf16 storage helpers (fp32 math everywhere) ----------
__device__ __forceinline__ float bf2f(u16 u){ return __uint_as_float(((u32)u)<<16); }
__device__ __forceinline__ float lo16(u32 u){ return __uint_as_float(u<<16); }
__device__ __forceinline__ float hi16(u32 u){ return __uint_as_float(u & 0xffff0000u); }
__device__ __forceinline__ u16 f2bf(float f){
  u32 x = __float_as_uint(f);
  x += 0x7fffu + ((x>>16)&1u);      // round-to-nearest-even
  return (u16)(x>>16);
}
__device__ __forceinline__ float elu_f(float x){ return x>0.f ? x : __expf(x)-1.f; }
__device__ __forceinline__ float lrelu(float x){ return x>0.f ? x : 0.2f*x; }
__device__ __forceinline__ bf16x8 ld_frag(const u16* p){
  uint4 v = *(const uint4*)p;
  return __builtin_bit_cast(bf16x8, v);
}

// ---------- f32 -> bf16 weight conversion ----------
__global__ void k_f2b(const float* __restrict__ in, u16* __restrict__ out, int n){
  int t = blockIdx.x*256 + threadIdx.x;
  if (t < n) out[t] = f2bf(in[t]);
}

// ---------- mix_w softmax over graphs: w[(type*3+l)*2+i] ----------
__global__ void k_mixw(const float* __restrict__ mix_w, float* __restrict__ wsoft){
  int t = threadIdx.x;
  if (t < 6){
    float a0 = mix_w[t*2+0];
    float a1 = mix_w[t*2+1];
    float mx = fmaxf(a0,a1);
    float e0 = __expf(a0-mx), e1 = __expf(a1-mx);
    float s = e0+e1;
    wsoft[t*2+0] = e0/s; wsoft[t*2+1] = e1/s;
  }
}

// ================= CSR build (per graph, rebuilt every launch) =================
__global__ void k_count(const int* __restrict__ dst, int* __restrict__ cnt){
  int t = blockIdx.x*256 + threadIdx.x;
  if (t < EE) atomicAdd(&cnt[dst[t]], 1);
}

__global__ __launch_bounds__(1024) void k_scan(const int* __restrict__ cnt, int* __restrict__ row){
  __shared__ int wsum[16];
  __shared__ int base;
  if (threadIdx.x == 0) base = 0;
  __syncthreads();
  int lane = threadIdx.x & 63, wid = threadIdx.x >> 6;
  for (int start = 0; start < NN; start += 1024){
    int i = start + threadIdx.x;
    int v = (i < NN) ? cnt[i] : 0;
    int x = v;
    #pragma unroll
    for (int off = 1; off < 64; off <<= 1){
      int y = __shfl_up(x, off, 64);
      if (lane >= off) x += y;
    }
    if (lane == 63) wsum[wid] = x;
    __syncthreads();
    if (wid == 0 && lane < 16){
      int s = wsum[lane];
      #pragma unroll
      for (int off = 1; off < 16; off <<= 1){
        int y = __shfl_up(s, off, 16);
        if (lane >= off) s += y;
      }
      wsum[lane] = s;
    }
    __syncthreads();
    int incl = x + (wid ? wsum[wid-1] : 0) + base;
    if (i < NN) row[i] = incl - v;     // exclusive
    __syncthreads();
    if (threadIdx.x == 1023) base = incl;
    __syncthreads();
  }
  if (threadIdx.x == 0) row[NN] = base;   // == EE
}

__global__ void k_scatter(const int* __restrict__ src, const int* __restrict__ dst,
                          const int* __restrict__ row, int* __restrict__ fill,
                          int* __restrict__ col){
  int t = blockIdx.x*256 + threadIdx.x;
  if (t >= EE) return;
  int d = dst[t];
  int pos = atomicAdd(&fill[d], 1);
  col[row[d] + pos] = src[t];
}

// ---------- input projection: h(N,64) = feat_t @ fc_w_t + fc_b_t (f32 in, bf16 out)
__global__ __launch_bounds__(256) void k_in_proj(
    const float* __restrict__ f0, const float* __restrict__ f1,
    const float* __restrict__ w0, const float* __restrict__ b0,
    const float* __restrict__ w1, const float* __restrict__ b1,
    u16* __restrict__ h)
{
  __shared__ float fs[4][128];
  int wv = threadIdx.x>>6, ln = threadIdx.x&63;
  int n = blockIdx.x*4 + wv;                // N divisible by 4
  const float *fr, *W, *B;
  if (n < NN0){ fr = f0 + (size_t)n*128; W=w0; B=b0; }
  else        { fr = f1 + (size_t)(n-NN0)*128; W=w1; B=b1; }
  float2 u = ((const float2*)fr)[ln];
  fs[wv][2*ln]   = u.x;
  fs[wv][2*ln+1] = u.y;
  __syncthreads();
  float acc = B[ln];
  #pragma unroll 8
  for (int k=0;k<128;k++) acc = fmaf(fs[wv][k], W[k*64+ln], acc);
  h[(size_t)n*64 + ln] = f2bf(acc);
}

// ---------- pack W (f32, K x 256 row-major) into MFMA B-fragment order ----------
// Bp[((ct*KB + kb)*64 + lane)*8 + j] = bf16(W[kb*32 + (lane>>4)*8 + j][ct*16 + (lane&15)])
__global__ void k_pack(const float* __restrict__ W, u16* __restrict__ Bp, int KB){
  int t = blockIdx.x*256 + threadIdx.x;
  if (t >= 16*KB*64) return;
  int lane = t & 63;
  int kb = (t>>6) % KB;
  int ct = (t>>6) / KB;
  int q = lane>>4, c = lane&15;
  u16* o = Bp + (size_t)t*8;
  #pragma unroll
  for (int j=0;j<8;j++)
    o[j] = f2bf(W[(size_t)(kb*32 + q*8 + j)*256 + ct*16 + c]);
}

// ---------- MFMA GEMM: feat(N,256) = A(N,K) @ W(K,256), fused el/er epilogue ----
// one wave = 16 rows x 256 cols (16 C-tiles). A bf16 row-major; Bp packed frags.
template<int K>
__global__ __launch_bounds__(256) void k_gemm(
    const u16* __restrict__ A, const u16* __restrict__ Bp,
    const float* __restrict__ al, const float* __restrict__ ar,
    u16* __restrict__ feat, float* __restrict__ el, float* __restrict__ er)
{
  constexpr int KB = K/32;
  int wv = threadIdx.x>>6, ln = threadIdx.x&63;
  int wt = blockIdx.x*4 + wv;            // wave tile id (16 rows each)
  if (wt >= NN/16) return;
  int row0 = wt*16;
  int q = ln>>4, c = ln&15;

  f32x4 acc[16] = {};
  const u16* Ap = A + (size_t)(row0 + c)*K + q*8;
  #pragma unroll
  for (int kb=0; kb<KB; kb++){
    bf16x8 a = ld_frag(Ap + kb*32);
    #pragma unroll
    for (int t=0;t<16;t++){
      bf16x8 b = ld_frag(Bp + ((size_t)(t*KB + kb)*64 + ln)*8);
      acc[t] = __builtin_amdgcn_mfma_f32_16x16x32_bf16(a, b, acc[t], 0,0,0);
    }
  }

  // attention coefficient epilogue: el/er per (row, head)
  float alv[16], arv[16];
  #pragma unroll
  for (int t=0;t<16;t++){ alv[t] = al[t*16+c]; arv[t] = ar[t*16+c]; }
  #pragma unroll
  for (int j=0;j<4;j++){
    #pragma unroll
    for (int h=0;h<4;h++){
      float ep=0.f, rp=0.f;
      #pragma unroll
      for (int t=4*h;t<4*h+4;t++){ ep += acc[t][j]*alv[t]; rp += acc[t][j]*arv[t]; }
      #pragma unroll
      for (int off=8; off; off>>=1){ ep += __shfl_xor(ep,off,16); rp += __shfl_xor(rp,off,16); }
      if (c==0){
        int row = row0 + q*4 + j;
        el[row*4+h] = ep; er[row*4+h] = rp;
      }
    }
  }

  // store feat (bf16). C layout: row = q*4+j, col = t*16+c
  #pragma unroll
  for (int t=0;t<16;t++){
    #pragma unroll
    for (int j=0;j<4;j++){
      int row = row0 + q*4 + j;
      feat[(size_t)row*256 + t*16 + c] = f2bf(acc[t][j]);
    }
  }
}

// ---------- gather aggregation, layers 0/1 (256 cols, H=4) ----------
template<int RES>
__global__ __launch_bounds__(256) void k_aggN(
    const int* __restrict__ row, const int* __restrict__ col,
    const u16* __restrict__ feat, const float* __restrict__ el, const float* __restrict__ er,
    const u16* __restrict__ hres, const float* __restrict__ bias,
    const float* __restrict__ wsoft, int l, int i, int first,
    u16* __restrict__ hout)
{
  int wv = threadIdx.x>>6, ln = threadIdx.x&63;
  int n = blockIdx.x*4 + wv;
  int h = ln>>4;
  int beg = row[n], end = row[n+1];
  float er_h = er[n*4+h];
  float m = -1e30f, den = 0.f;
  for (int k=beg; k<end; k++){
    int s = col[k];
    float e = lrelu(el[s*4+h] + er_h);
    float mn = fmaxf(m, e);
    den = den*__expf(m-mn) + __expf(e-mn);
    m = mn;
  }
  float inv = (end>beg) ? 1.0f/den : 0.f;
  float a0=0.f,a1=0.f,a2=0.f,a3=0.f;
  for (int k=beg; k<end; k++){
    int s = col[k];
    float e = lrelu(el[s*4+h] + er_h);
    float a = __expf(e-m)*inv;
    uint2 f = ((const uint2*)feat)[(size_t)s*64 + ln];
    a0 = fmaf(a, lo16(f.x), a0);
    a1 = fmaf(a, hi16(f.x), a1);
    a2 = fmaf(a, lo16(f.y), a2);
    a3 = fmaf(a, hi16(f.y), a3);
  }
  float4 bv = ((const float4*)bias)[ln];
  a0 += bv.x; a1 += bv.y; a2 += bv.z; a3 += bv.w;
  if (RES){
    uint2 r = ((const uint2*)hres)[(size_t)n*64 + ln];
    a0 += lo16(r.x); a1 += hi16(r.x); a2 += lo16(r.y); a3 += hi16(r.y);
  }
  a0 = elu_f(a0); a1 = elu_f(a1); a2 = elu_f(a2); a3 = elu_f(a3);
  float w = wsoft[((n<NN0)?0:1)*6 + l*2 + i];
  a0 *= w; a1 *= w; a2 *= w; a3 *= w;
  if (!first){
    uint2 p = ((const uint2*)hout)[(size_t)n*64 + ln];
    a0 += lo16(p.x); a1 += hi16(p.x); a2 += lo16(p.y); a3 += hi16(p.y);
  }
  uint2 o;
  o.x = (u32)f2bf(a0) | ((u32)f2bf(a1)<<16);
  o.y = (u32)f2bf(a2) | ((u32)f2bf(a3)<<16);
  ((uint2*)hout)[(size_t)n*64 + ln] = o;
}

// ---------- layer-2 GEMM (256 -> 16) + el/er epilogue ----------
__global__ __launch_bounds__(256) void k_feat16(
    const u16* __restrict__ hin, const u16* __restrict__ Wb,
    const float* __restrict__ al, const float* __restrict__ ar,
    float* __restrict__ feat16, float* __restrict__ el, float* __restrict__ er)
{
  __shared__ u16 hs[16*256];
  int t = threadIdx.x;
  const uint2* g = (const uint2*)(hin + (size_t)blockIdx.x*16*256);
  uint2* hs2 = (uint2*)hs;
  #pragma unroll
  for (int q=0;q<4;q++) hs2[t + q*256] = g[t + q*256];
  __syncthreads();
  int nl = t>>4, j = t&15;
  int n = blockIdx.x*16 + nl;
  const u16* hr = hs + nl*256;
  float acc=0.f;
  #pragma unroll 8
  for (int k=0;k<256;k++) acc = fmaf(bf2f(hr[k]), bf2f(Wb[k*16+j]), acc);
  float ep = acc*al[j];
  float rp = acc*ar[j];
  for (int off=8; off; off>>=1){ ep += __shfl_xor(ep,off,16); rp += __shfl_xor(rp,off,16); }
  if (j==0){ el[n]=ep; er[n]=rp; }
  feat16[(size_t)n*16+j] = acc;
}

// ---------- layer-2 fc residual: resb = h @ res2 (f32, no bias) ----------
__global__ __launch_bounds__(256) void k_res16(
    const u16* __restrict__ hin, const u16* __restrict__ Rb, float* __restrict__ resb)
{
  __shared__ u16 hs[16*256];
  int t = threadIdx.x;
  const uint2* g = (const uint2*)(hin + (size_t)blockIdx.x*16*256);
  uint2* hs2 = (uint2*)hs;
  #pragma unroll
  for (int q=0;q<4;q++) hs2[t + q*256] = g[t + q*256];
  __syncthreads();
  int nl = t>>4, j = t&15;
  int n = blockIdx.x*16 + nl;
  const u16* hr = hs + nl*256;
  float acc = 0.f;
  #pragma unroll 8
  for (int k=0;k<256;k++) acc = fmaf(bf2f(hr[k]), bf2f(Rb[k*16+j]), acc);
  resb[(size_t)n*16+j] = acc;
}

// ---------- layer-2 gather aggregation (16 cols, H=1) + final mix (f32 out) ----
__global__ __launch_bounds__(256) void k_agg2(
    const int* __restrict__ row, const int* __restrict__ col,
    const float* __restrict__ feat16, const float* __restrict__ el, const float* __restrict__ er,
    const float* __restrict__ resb, const float* __restrict__ b2,
    const float* __restrict__ wsoft, int i, int first, float* __restrict__ out)
{
  int t = threadIdx.x;
  int nl = t>>4, j = t&15;
  int n = blockIdx.x*16 + nl;
  int beg = row[n], end = row[n+1];
  float ern = er[n];
  float m = -1e30f, den = 0.f;
  for (int k=beg; k<end; k++){
    float e = lrelu(el[col[k]] + ern);
    float mn = fmaxf(m, e);
    den = den*__expf(m-mn) + __expf(e-mn);
    m = mn;
  }
  float inv = (end>beg) ? 1.0f/den : 0.f;
  float acc = 0.f;
  for (int k=beg; k<end; k++){
    int s = col[k];
    float e = lrelu(el[s] + ern);
    acc = fmaf(__expf(e-m)*inv, feat16[(size_t)s*16+j], acc);
  }
  float o = acc + b2[j] + resb[(size_t)n*16+j];
  float w = wsoft[((n<NN0)?0:1)*6 + 4 + i];
  float r = o*w;
  if (!first) r += out[(size_t)n*16+j];
  out[(size_t)n*16+j] = r;
}

extern "C" void kernel_launch(void* const* d_in, const int* in_sizes, int n_in,
                              void* d_out, int out_size, void* d_ws, size_t ws_size,
                              hipStream_t stream)
{
  const float* features0 = (const float*)d_in[0];
  const float* features1 = (const float*)d_in[1];
  const float* fc_w0 = (const float*)d_in[2];
  const float* fc_b0 = (const float*)d_in[3];
  const float* fc_w1 = (const float*)d_in[4];
  const float* fc_b1 = (const float*)d_in[5];
  const float* mix_w = (const float*)d_in[6];
  const float* W0  = (const float*)d_in[7];
  const float* al0 = (const float*)d_in[8];
  const float* ar0 = (const float*)d_in[9];
  const float* b0  = (const float*)d_in[10];
  const float* W1  = (const float*)d_in[11];
  const float* al1 = (const float*)d_in[12];
  const float* ar1 = (const float*)d_in[13];
  const float* b1  = (const float*)d_in[14];
  const float* W2  = (const float*)d_in[15];
  const float* al2 = (const float*)d_in[16];
  const float* ar2 = (const float*)d_in[17];
  const float* b2  = (const float*)d_in[18];
  const float* res2= (const float*)d_in[19];
  const int* src[2] = {(const int*)d_in[20], (const int*)d_in[22]};
  const int* dst[2] = {(const int*)d_in[21], (const int*)d_in[23]};
  (void)in_sizes; (void)n_in; (void)out_size; (void)ws_size;

  // workspace layout (~90 MB)
  char* ws = (char*)d_ws;
  size_t off = 0;
  auto alloc = [&](size_t bytes)->char*{
    char* p = ws + off; off += (bytes + 255) & ~(size_t)255; return p;
  };
  float* wsoft = (float*)alloc(64*4);
  u16*   hA    = (u16*)  alloc((size_t)NN*256*2);
  u16*   hB    = (u16*)  alloc((size_t)NN*256*2);
  u16*   feat  = (u16*)  alloc((size_t)NN*256*2);
  float* el    = (float*)alloc((size_t)NN*4*4);
  float* er    = (float*)alloc((size_t)NN*4*4);
  float* resb  = (float*)alloc((size_t)NN*16*4);
  float* feat16= (float*)alloc((size_t)NN*16*4);
  u16*   W0p   = (u16*)  alloc((size_t)2*64*256*2);   // packed B-frags, layer0
  u16*   W1p   = (u16*)  alloc((size_t)2*256*256*2);  // packed B-frags, layer1
  u16*   W2b   = (u16*)  alloc((size_t)2*256*16*2);
  u16*   R2b   = (u16*)  alloc((size_t)2*256*16*2);
  int*   rowg[2]; int* colg[2];
  rowg[0] = (int*)alloc((size_t)(NN+1)*4);
  colg[0] = (int*)alloc((size_t)EE*4);
  rowg[1] = (int*)alloc((size_t)(NN+1)*4);
  colg[1] = (int*)alloc((size_t)EE*4);
  int*   cnt   = (int*)alloc((size_t)NN*4);
  int*   fill  = (int*)alloc((size_t)NN*4);

  k_mixw<<<1,64,0,stream>>>(mix_w, wsoft);

  // pack GEMM weights into MFMA B-fragment order (bf16)
  for (int i=0;i<2;i++){
    k_pack<<<(16*2*64+255)/256,256,0,stream>>>(W0+(size_t)i*64*256,  W0p+(size_t)i*64*256,  2);
    k_pack<<<(16*8*64+255)/256,256,0,stream>>>(W1+(size_t)i*256*256, W1p+(size_t)i*256*256, 8);
  }
  k_f2b<<<(2*256*16+255)/256,256,0,stream>>>(W2,  W2b, 2*256*16);
  k_f2b<<<(2*256*16+255)/256,256,0,stream>>>(res2,R2b, 2*256*16);

  // Build CSR (dst-sorted adjacency) per graph — int atomics only
  for (int g=0; g<2; g++){
    hipMemsetAsync(cnt,  0, (size_t)NN*4, stream);
    hipMemsetAsync(fill, 0, (size_t)NN*4, stream);
    k_count  <<<(EE+255)/256,256,0,stream>>>(dst[g], cnt);
    k_scan   <<<1,1024,0,stream>>>(cnt, rowg[g]);
    k_scatter<<<(EE+255)/256,256,0,stream>>>(src[g], dst[g], rowg[g], fill, colg[g]);
  }

  k_in_proj<<<NN/4,256,0,stream>>>(features0, features1, fc_w0, fc_b0, fc_w1, fc_b1, hA);

  const int GEMM_BLOCKS = (NN/16 + 3)/4;   // 3125 wave-tiles / 4 waves per block

  // layer 0: h (N,64) -> hB (N,256); no residual
  for (int i=0; i<2; i++){
    k_gemm<64><<<GEMM_BLOCKS,256,0,stream>>>(hA, W0p+(size_t)i*64*256, al0+i*256, ar0+i*256, feat, el, er);
    k_aggN<0><<<NN/4,256,0,stream>>>(rowg[i], colg[i], feat, el, er,
                                     (const u16*)nullptr, b0+i*256, wsoft, 0, i, (i==0)?1:0, hB);
  }
  // layer 1: hB (N,256) -> hA (N,256); identity residual
  for (int i=0; i<2; i++){
    k_gemm<256><<<GEMM_BLOCKS,256,0,stream>>>(hB, W1p+(size_t)i*256*256, al1+i*256, ar1+i*256, feat, el, er);
    k_aggN<1><<<NN/4,256,0,stream>>>(rowg[i], colg[i], feat, el, er,
                                     hB, b1+i*256, wsoft, 1, i, (i==0)?1:0, hA);
  }
  // layer 2: hA (N,256) -> logits (N,16); fc residual, no activation
  for (int i=0; i<2; i++){
    k_feat16<<<NN/16,256,0,stream>>>(hA, W2b+(size_t)i*256*16, al2+i*16, ar2+i*16, feat16, el, er);
    k_res16 <<<NN/16,256,0,stream>>>(hA, R2b+(size_t)i*256*16, resb);
    k_agg2  <<<NN/16,256,0,stream>>>(rowg[i], colg[i], feat16, el, er, resb, b2+i*16,
                                     wsoft, i, (i==0)?1:0, (float*)d_out);
  }
}

// Round 5
// 646.076 us; speedup vs baseline: 2.8309x; 1.6924x over previous
//
#include <hip/hip_runtime.h>
#include <hip/hip_bf16.h>

// Problem constants (match reference)
#define NN   50000   // N0+N1
#define NN0  30000
#define EE   400000
#define NB_SCAN ((NN + 1023) / 1024)   // 49

typedef unsigned short u16;
typedef unsigned int   u32;

typedef __attribute__((ext_vector_type(8))) __bf16 bf16x8;
typedef __attribute__((ext_vector_type(4))) float  f32x4;

// ---------- bf16 storage helpers (fp32 math everywhere) ----------
__device__ __forceinline__ float bf2f(u16 u){ return __uint_as_float(((u32)u)<<16); }
__device__ __forceinline__ float lo16(u32 u){ return __uint_as_float(u<<16); }
__device__ __forceinline__ float hi16(u32 u){ return __uint_as_float(u & 0xffff0000u); }
__device__ __forceinline__ u16 f2bf(float f){
  u32 x = __float_as_uint(f);
  x += 0x7fffu + ((x>>16)&1u);      // round-to-nearest-even
  return (u16)(x>>16);
}
__device__ __forceinline__ float elu_f(float x){ return x>0.f ? x : __expf(x)-1.f; }
__device__ __forceinline__ float lrelu(float x){ return x>0.f ? x : 0.2f*x; }
__device__ __forceinline__ bf16x8 ld_frag(const u16* p){
  uint4 v = *(const uint4*)p;
  return __builtin_bit_cast(bf16x8, v);
}

// ---------- mix_w softmax over graphs: w[(type*3+l)*2+i] ----------
__global__ void k_mixw(const float* __restrict__ mix_w, float* __restrict__ wsoft){
  int t = threadIdx.x;
  if (t < 6){
    float a0 = mix_w[t*2+0];
    float a1 = mix_w[t*2+1];
    float mx = fmaxf(a0,a1);
    float e0 = __expf(a0-mx), e1 = __expf(a1-mx);
    float s = e0+e1;
    wsoft[t*2+0] = e0/s; wsoft[t*2+1] = e1/s;
  }
}

// ================= CSR build (per graph, rebuilt every launch) =================
__global__ void k_count(const int* __restrict__ dst, int* __restrict__ cnt){
  int t = blockIdx.x*256 + threadIdx.x;
  if (t < EE) atomicAdd(&cnt[dst[t]], 1);
}

// 3-stage exclusive scan: per-block scan -> scan of block sums -> add offsets
__global__ __launch_bounds__(1024) void k_scan1(const int* __restrict__ cnt,
                                                int* __restrict__ row, int* __restrict__ bsum){
  __shared__ int wsum[16];
  int lane = threadIdx.x & 63, wid = threadIdx.x >> 6;
  int i = blockIdx.x*1024 + threadIdx.x;
  int v = (i < NN) ? cnt[i] : 0;
  int x = v;
  #pragma unroll
  for (int off = 1; off < 64; off <<= 1){
    int y = __shfl_up(x, off, 64);
    if (lane >= off) x += y;
  }
  if (lane == 63) wsum[wid] = x;
  __syncthreads();
  if (wid == 0 && lane < 16){
    int s = wsum[lane];
    #pragma unroll
    for (int off = 1; off < 16; off <<= 1){
      int y = __shfl_up(s, off, 16);
      if (lane >= off) s += y;
    }
    wsum[lane] = s;
  }
  __syncthreads();
  int incl = x + (wid ? wsum[wid-1] : 0);
  if (i < NN) row[i] = incl - v;          // block-local exclusive
  if (threadIdx.x == 1023) bsum[blockIdx.x] = incl;
}

__global__ __launch_bounds__(64) void k_scan2(const int* __restrict__ bsum, int* __restrict__ boff){
  int lane = threadIdx.x;
  int v = (lane < NB_SCAN) ? bsum[lane] : 0;
  int x = v;
  #pragma unroll
  for (int off = 1; off < 64; off <<= 1){
    int y = __shfl_up(x, off, 64);
    if (lane >= off) x += y;
  }
  if (lane < NB_SCAN) boff[lane] = x - v;  // exclusive
}

__global__ __launch_bounds__(1024) void k_scan3(int* __restrict__ row, const int* __restrict__ boff){
  int i = blockIdx.x*1024 + threadIdx.x;
  if (i < NN) row[i] += boff[blockIdx.x];
  if (blockIdx.x == 0 && threadIdx.x == 0) row[NN] = EE;
}

__global__ void k_scatter(const int* __restrict__ src, const int* __restrict__ dst,
                          const int* __restrict__ row, int* __restrict__ fill,
                          int* __restrict__ col){
  int t = blockIdx.x*256 + threadIdx.x;
  if (t >= EE) return;
  int d = dst[t];
  int pos = atomicAdd(&fill[d], 1);
  col[row[d] + pos] = src[t];
}

// ---------- input projection: h(N,64) = feat_t @ fc_w_t + fc_b_t (f32 in, bf16 out)
__global__ __launch_bounds__(256) void k_in_proj(
    const float* __restrict__ f0, const float* __restrict__ f1,
    const float* __restrict__ w0, const float* __restrict__ b0,
    const float* __restrict__ w1, const float* __restrict__ b1,
    u16* __restrict__ h)
{
  __shared__ float fs[4][128];
  int wv = threadIdx.x>>6, ln = threadIdx.x&63;
  int n = blockIdx.x*4 + wv;                // N divisible by 4
  const float *fr, *W, *B;
  if (n < NN0){ fr = f0 + (size_t)n*128; W=w0; B=b0; }
  else        { fr = f1 + (size_t)(n-NN0)*128; W=w1; B=b1; }
  float2 u = ((const float2*)fr)[ln];
  fs[wv][2*ln]   = u.x;
  fs[wv][2*ln+1] = u.y;
  __syncthreads();
  float acc = B[ln];
  #pragma unroll 8
  for (int k=0;k<128;k++) acc = fmaf(fs[wv][k], W[k*64+ln], acc);
  h[(size_t)n*64 + ln] = f2bf(acc);
}

// ---------- pack W (f32, K x NCOL row-major) into MFMA B-fragment order ----------
// Bp[((ct*KB + kb)*64 + lane)*8 + j] = bf16(W[kb*32 + (lane>>4)*8 + j][ct*16 + (lane&15)])
template<int NCOL>
__global__ void k_pack(const float* __restrict__ W, u16* __restrict__ Bp, int KB){
  int t = blockIdx.x*256 + threadIdx.x;
  if (t >= (NCOL/16)*KB*64) return;
  int lane = t & 63;
  int kb = (t>>6) % KB;
  int ct = (t>>6) / KB;
  int q = lane>>4, c = lane&15;
  u16* o = Bp + (size_t)t*8;
  #pragma unroll
  for (int j=0;j<8;j++)
    o[j] = f2bf(W[(size_t)(kb*32 + q*8 + j)*NCOL + ct*16 + c]);
}

// ---------- concat [W2_0 | res2_0 | W2_1 | res2_1] into 256 x 64 (f32) ----------
__global__ void k_cat(const float* __restrict__ W2, const float* __restrict__ res2,
                      float* __restrict__ M){
  int t = blockIdx.x*256 + threadIdx.x;   // 256*64
  if (t >= 256*64) return;
  int row = t>>6, cl = t&63;
  int i = cl>>5, which = (cl>>4)&1, j = cl&15;
  const float* src = which ? res2 : W2;
  M[t] = src[(size_t)i*256*16 + row*16 + j];
}

// ---------- MFMA GEMM: feat(N,256) = A(N,K) @ W(K,256), fused el/er epilogue ----
template<int K>
__global__ __launch_bounds__(256) void k_gemm(
    const u16* __restrict__ A, const u16* __restrict__ Bp,
    const float* __restrict__ al, const float* __restrict__ ar,
    u16* __restrict__ feat, float* __restrict__ el, float* __restrict__ er)
{
  constexpr int KB = K/32;
  int wv = threadIdx.x>>6, ln = threadIdx.x&63;
  int wt = blockIdx.x*4 + wv;            // wave tile id (16 rows each)
  if (wt >= NN/16) return;
  int row0 = wt*16;
  int q = ln>>4, c = ln&15;

  f32x4 acc[16] = {};
  const u16* Ap = A + (size_t)(row0 + c)*K + q*8;
  #pragma unroll
  for (int kb=0; kb<KB; kb++){
    bf16x8 a = ld_frag(Ap + kb*32);
    #pragma unroll
    for (int t=0;t<16;t++){
      bf16x8 b = ld_frag(Bp + ((size_t)(t*KB + kb)*64 + ln)*8);
      acc[t] = __builtin_amdgcn_mfma_f32_16x16x32_bf16(a, b, acc[t], 0,0,0);
    }
  }

  // attention coefficient epilogue: el/er per (row, head)
  float alv[16], arv[16];
  #pragma unroll
  for (int t=0;t<16;t++){ alv[t] = al[t*16+c]; arv[t] = ar[t*16+c]; }
  #pragma unroll
  for (int j=0;j<4;j++){
    #pragma unroll
    for (int h=0;h<4;h++){
      float ep=0.f, rp=0.f;
      #pragma unroll
      for (int t=4*h;t<4*h+4;t++){ ep += acc[t][j]*alv[t]; rp += acc[t][j]*arv[t]; }
      #pragma unroll
      for (int off=8; off; off>>=1){ ep += __shfl_xor(ep,off,16); rp += __shfl_xor(rp,off,16); }
      if (c==0){
        int row = row0 + q*4 + j;
        el[row*4+h] = ep; er[row*4+h] = rp;
      }
    }
  }

  // store feat (bf16). C layout: row = q*4+j, col = t*16+c
  #pragma unroll
  for (int t=0;t<16;t++){
    #pragma unroll
    for (int j=0;j<4;j++){
      int row = row0 + q*4 + j;
      feat[(size_t)row*256 + t*16 + c] = f2bf(acc[t][j]);
    }
  }
}

// ---------- gather aggregation, layers 0/1 (256 cols, H=4) ----------
// one wave per node; lane = 4 contiguous cols; head = lane>>4.
// SINGLE-PASS softmax (shift-invariant; |e| small so exp cannot overflow):
//   den += exp(e);  acc += exp(e)*feat[src];  out = acc/den
// unrolled x4 so 4 feat gathers are in flight per wave.
template<int RES>
__global__ __launch_bounds__(256) void k_aggN(
    const int* __restrict__ row, const int* __restrict__ col,
    const u16* __restrict__ feat, const float* __restrict__ el, const float* __restrict__ er,
    const u16* __restrict__ hres, const float* __restrict__ bias,
    const float* __restrict__ wsoft, int l, int i, int first,
    u16* __restrict__ hout)
{
  int wv = threadIdx.x>>6, ln = threadIdx.x&63;
  int n = blockIdx.x*4 + wv;
  int h = ln>>4;
  int beg = row[n], end = row[n+1];
  float er_h = er[n*4+h];
  const uint2* fp = (const uint2*)feat;
  float den = 0.f;
  float a0=0.f,a1=0.f,a2=0.f,a3=0.f;
  int k = beg;
  for (; k+4<=end; k+=4){
    int s0=col[k], s1=col[k+1], s2=col[k+2], s3=col[k+3];
    float x0 = __expf(lrelu(el[s0*4+h] + er_h));
    float x1 = __expf(lrelu(el[s1*4+h] + er_h));
    float x2 = __expf(lrelu(el[s2*4+h] + er_h));
    float x3 = __expf(lrelu(el[s3*4+h] + er_h));
    uint2 f0 = fp[(size_t)s0*64 + ln];
    uint2 f1 = fp[(size_t)s1*64 + ln];
    uint2 f2 = fp[(size_t)s2*64 + ln];
    uint2 f3 = fp[(size_t)s3*64 + ln];
    den += (x0+x1) + (x2+x3);
    a0 += x0*lo16(f0.x) + x1*lo16(f1.x) + x2*lo16(f2.x) + x3*lo16(f3.x);
    a1 += x0*hi16(f0.x) + x1*hi16(f1.x) + x2*hi16(f2.x) + x3*hi16(f3.x);
    a2 += x0*lo16(f0.y) + x1*lo16(f1.y) + x2*lo16(f2.y) + x3*lo16(f3.y);
    a3 += x0*hi16(f0.y) + x1*hi16(f1.y) + x2*hi16(f2.y) + x3*hi16(f3.y);
  }
  for (; k<end; k++){
    int s = col[k];
    float x = __expf(lrelu(el[s*4+h] + er_h));
    uint2 f = fp[(size_t)s*64 + ln];
    den += x;
    a0 += x*lo16(f.x); a1 += x*hi16(f.x); a2 += x*lo16(f.y); a3 += x*hi16(f.y);
  }
  float inv = (end>beg) ? 1.0f/den : 0.f;
  a0 *= inv; a1 *= inv; a2 *= inv; a3 *= inv;

  float4 bv = ((const float4*)bias)[ln];
  a0 += bv.x; a1 += bv.y; a2 += bv.z; a3 += bv.w;
  if (RES){
    uint2 r = ((const uint2*)hres)[(size_t)n*64 + ln];
    a0 += lo16(r.x); a1 += hi16(r.x); a2 += lo16(r.y); a3 += hi16(r.y);
  }
  a0 = elu_f(a0); a1 = elu_f(a1); a2 = elu_f(a2); a3 = elu_f(a3);
  float w = wsoft[((n<NN0)?0:1)*6 + l*2 + i];
  a0 *= w; a1 *= w; a2 *= w; a3 *= w;
  if (!first){
    uint2 p = ((const uint2*)hout)[(size_t)n*64 + ln];
    a0 += lo16(p.x); a1 += hi16(p.x); a2 += lo16(p.y); a3 += hi16(p.y);
  }
  uint2 o;
  o.x = (u32)f2bf(a0) | ((u32)f2bf(a1)<<16);
  o.y = (u32)f2bf(a2) | ((u32)f2bf(a3)<<16);
  ((uint2*)hout)[(size_t)n*64 + ln] = o;
}

// ---------- layer-2 MFMA: A(N,256) @ [W2_0|res2_0|W2_1|res2_1](256,64) ----------
// one wave = 16 rows x 64 cols (4 C-tiles: feat16_0, resb_0, feat16_1, resb_1)
__global__ __launch_bounds__(256) void k_gemm2(
    const u16* __restrict__ A, const u16* __restrict__ Bp,
    const float* __restrict__ al2, const float* __restrict__ ar2,   // [2][16]
    float* __restrict__ feat16, float* __restrict__ resb,           // [2][NN*16]
    float* __restrict__ el2, float* __restrict__ er2)               // [2][NN]
{
  int wv = threadIdx.x>>6, ln = threadIdx.x&63;
  int wt = blockIdx.x*4 + wv;
  if (wt >= NN/16) return;
  int row0 = wt*16;
  int q = ln>>4, c = ln&15;
  f32x4 acc[4] = {};
  const u16* Ap = A + (size_t)(row0 + c)*256 + q*8;
  #pragma unroll
  for (int kb=0; kb<8; kb++){
    bf16x8 a = ld_frag(Ap + kb*32);
    #pragma unroll
    for (int t=0;t<4;t++){
      bf16x8 b = ld_frag(Bp + ((size_t)(t*8 + kb)*64 + ln)*8);
      acc[t] = __builtin_amdgcn_mfma_f32_16x16x32_bf16(a, b, acc[t], 0,0,0);
    }
  }
  #pragma unroll
  for (int i=0;i<2;i++){
    float alv = al2[i*16+c], arv = ar2[i*16+c];
    #pragma unroll
    for (int j=0;j<4;j++){
      float ep = acc[2*i][j]*alv, rp = acc[2*i][j]*arv;
      #pragma unroll
      for (int off=8; off; off>>=1){ ep += __shfl_xor(ep,off,16); rp += __shfl_xor(rp,off,16); }
      if (c==0){
        int row = row0 + q*4 + j;
        el2[(size_t)i*NN + row] = ep; er2[(size_t)i*NN + row] = rp;
      }
    }
    #pragma unroll
    for (int j=0;j<4;j++){
      int row = row0 + q*4 + j;
      feat16[(size_t)i*NN*16 + (size_t)row*16 + c] = acc[2*i][j];
      resb  [(size_t)i*NN*16 + (size_t)row*16 + c] = acc[2*i+1][j];
    }
  }
}

// ---------- layer-2 dual-graph aggregation (16 cols, H=1) + final mix (f32 out)
__global__ __launch_bounds__(256) void k_agg2D(
    const int* __restrict__ row0, const int* __restrict__ col0,
    const int* __restrict__ row1, const int* __restrict__ col1,
    const float* __restrict__ feat16, const float* __restrict__ el2,
    const float* __restrict__ er2, const float* __restrict__ resb,
    const float* __restrict__ b2, const float* __restrict__ wsoft,
    float* __restrict__ out)
{
  int t = threadIdx.x;
  int nl = t>>4, j = t&15;
  int n = blockIdx.x*16 + nl;
  int type = (n<NN0)?0:1;
  float o = 0.f;
  #pragma unroll
  for (int i=0;i<2;i++){
    const int* rw = i ? row1 : row0;
    const int* cl = i ? col1 : col0;
    const float* f  = feat16 + (size_t)i*NN*16;
    const float* eli= el2 + (size_t)i*NN;
    float ern = er2[(size_t)i*NN + n];
    int beg = rw[n], end = rw[n+1];
    float den = 0.f, acc = 0.f;
    int k = beg;
    for (; k+4<=end; k+=4){
      int s0=cl[k], s1=cl[k+1], s2=cl[k+2], s3=cl[k+3];
      float x0 = __expf(lrelu(eli[s0] + ern));
      float x1 = __expf(lrelu(eli[s1] + ern));
      float x2 = __expf(lrelu(eli[s2] + ern));
      float x3 = __expf(lrelu(eli[s3] + ern));
      float v0 = f[(size_t)s0*16 + j];
      float v1 = f[(size_t)s1*16 + j];
      float v2 = f[(size_t)s2*16 + j];
      float v3 = f[(size_t)s3*16 + j];
      den += (x0+x1) + (x2+x3);
      acc += x0*v0 + x1*v1 + x2*v2 + x3*v3;
    }
    for (; k<end; k++){
      int s = cl[k];
      float x = __expf(lrelu(eli[s] + ern));
      den += x;
      acc = fmaf(x, f[(size_t)s*16 + j], acc);
    }
    float inv = (end>beg) ? 1.0f/den : 0.f;
    float oi = acc*inv + b2[i*16+j] + resb[(size_t)i*NN*16 + (size_t)n*16 + j];
    o += oi * wsoft[type*6 + 4 + i];
  }
  out[(size_t)n*16 + j] = o;
}

extern "C" void kernel_launch(void* const* d_in, const int* in_sizes, int n_in,
                              void* d_out, int out_size, void* d_ws, size_t ws_size,
                              hipStream_t stream)
{
  const float* features0 = (const float*)d_in[0];
  const float* features1 = (const float*)d_in[1];
  const float* fc_w0 = (const float*)d_in[2];
  const float* fc_b0 = (const float*)d_in[3];
  const float* fc_w1 = (const float*)d_in[4];
  const float* fc_b1 = (const float*)d_in[5];
  const float* mix_w = (const float*)d_in[6];
  const float* W0  = (const float*)d_in[7];
  const float* al0 = (const float*)d_in[8];
  const float* ar0 = (const float*)d_in[9];
  const float* b0  = (const float*)d_in[10];
  const float* W1  = (const float*)d_in[11];
  const float* al1 = (const float*)d_in[12];
  const float* ar1 = (const float*)d_in[13];
  const float* b1  = (const float*)d_in[14];
  const float* W2  = (const float*)d_in[15];
  const float* al2 = (const float*)d_in[16];
  const float* ar2 = (const float*)d_in[17];
  const float* b2  = (const float*)d_in[18];
  const float* res2= (const float*)d_in[19];
  const int* src[2] = {(const int*)d_in[20], (const int*)d_in[22]};
  const int* dst[2] = {(const int*)d_in[21], (const int*)d_in[23]};
  (void)in_sizes; (void)n_in; (void)out_size; (void)ws_size;

  // workspace layout (~97 MB)
  char* ws = (char*)d_ws;
  size_t off = 0;
  auto alloc = [&](size_t bytes)->char*{
    char* p = ws + off; off += (bytes + 255) & ~(size_t)255; return p;
  };
  float* wsoft = (float*)alloc(64*4);
  u16*   hA    = (u16*)  alloc((size_t)NN*256*2);
  u16*   hB    = (u16*)  alloc((size_t)NN*256*2);
  u16*   feat  = (u16*)  alloc((size_t)NN*256*2);
  float* el    = (float*)alloc((size_t)NN*4*4);
  float* er    = (float*)alloc((size_t)NN*4*4);
  float* el2   = (float*)alloc((size_t)2*NN*4);
  float* er2   = (float*)alloc((size_t)2*NN*4);
  float* feat16= (float*)alloc((size_t)2*NN*16*4);
  float* resb  = (float*)alloc((size_t)2*NN*16*4);
  u16*   W0p   = (u16*)  alloc((size_t)2*64*256*2);   // packed B-frags, layer0
  u16*   W1p   = (u16*)  alloc((size_t)2*256*256*2);  // packed B-frags, layer1
  float* M2    = (float*)alloc((size_t)256*64*4);     // concat layer2 weights f32
  u16*   W2p   = (u16*)  alloc((size_t)256*64*2);     // packed B-frags, layer2
  int*   rowg[2]; int* colg[2];
  rowg[0] = (int*)alloc((size_t)(NN+1)*4);
  colg[0] = (int*)alloc((size_t)EE*4);
  rowg[1] = (int*)alloc((size_t)(NN+1)*4);
  colg[1] = (int*)alloc((size_t)EE*4);
  int*   cnt   = (int*)alloc((size_t)NN*4);
  int*   fill  = (int*)alloc((size_t)NN*4);
  int*   bsum  = (int*)alloc((size_t)NB_SCAN*4);
  int*   boff  = (int*)alloc((size_t)NB_SCAN*4);

  k_mixw<<<1,64,0,stream>>>(mix_w, wsoft);

  // pack GEMM weights into MFMA B-fragment order (bf16)
  for (int i=0;i<2;i++){
    k_pack<256><<<(16*2*64+255)/256,256,0,stream>>>(W0+(size_t)i*64*256,  W0p+(size_t)i*64*256,  2);
    k_pack<256><<<(16*8*64+255)/256,256,0,stream>>>(W1+(size_t)i*256*256, W1p+(size_t)i*256*256, 8);
  }
  k_cat<<<(256*64+255)/256,256,0,stream>>>(W2, res2, M2);
  k_pack<64><<<(4*8*64+255)/256,256,0,stream>>>(M2, W2p, 8);

  // Build CSR (dst-sorted adjacency) per graph — int atomics only
  for (int g=0; g<2; g++){
    hipMemsetAsync(cnt,  0, (size_t)NN*4, stream);
    hipMemsetAsync(fill, 0, (size_t)NN*4, stream);
    k_count <<<(EE+255)/256,256,0,stream>>>(dst[g], cnt);
    k_scan1 <<<NB_SCAN,1024,0,stream>>>(cnt, rowg[g], bsum);
    k_scan2 <<<1,64,0,stream>>>(bsum, boff);
    k_scan3 <<<NB_SCAN,1024,0,stream>>>(rowg[g], boff);
    k_scatter<<<(EE+255)/256,256,0,stream>>>(src[g], dst[g], rowg[g], fill, colg[g]);
  }

  k_in_proj<<<NN/4,256,0,stream>>>(features0, features1, fc_w0, fc_b0, fc_w1, fc_b1, hA);

  const int GEMM_BLOCKS = (NN/16 + 3)/4;   // 3125 wave-tiles / 4 waves per block

  // layer 0: h (N,64) -> hB (N,256); no residual
  for (int i=0; i<2; i++){
    k_gemm<64><<<GEMM_BLOCKS,256,0,stream>>>(hA, W0p+(size_t)i*64*256, al0+i*256, ar0+i*256, feat, el, er);
    k_aggN<0><<<NN/4,256,0,stream>>>(rowg[i], colg[i], feat, el, er,
                                     (const u16*)nullptr, b0+i*256, wsoft, 0, i, (i==0)?1:0, hB);
  }
  // layer 1: hB (N,256) -> hA (N,256); identity residual
  for (int i=0; i<2; i++){
    k_gemm<256><<<GEMM_BLOCKS,256,0,stream>>>(hB, W1p+(size_t)i*256*256, al1+i*256, ar1+i*256, feat, el, er);
    k_aggN<1><<<NN/4,256,0,stream>>>(rowg[i], colg[i], feat, el, er,
                                     hB, b1+i*256, wsoft, 1, i, (i==0)?1:0, hA);
  }
  // layer 2: hA (N,256) -> logits (N,16); fc residual, no activation; both graphs fused
  k_gemm2<<<GEMM_BLOCKS,256,0,stream>>>(hA, W2p, al2, ar2, feat16, resb, el2, er2);
  k_agg2D<<<NN/16,256,0,stream>>>(rowg[0], colg[0], rowg[1], colg[1],
                                  feat16, el2, er2, resb, b2, wsoft, (float*)d_out);
}

// Round 6
// 496.802 us; speedup vs baseline: 3.6815x; 1.3005x over previous
//
#include <hip/hip_runtime.h>
#include <hip/hip_bf16.h>

// Problem constants (match reference)
#define NN   50000   // N0+N1
#define NN0  30000
#define EE   400000
#define NB_SCAN ((NN + 1023) / 1024)   // 49
#define NRT   3125                     // row tiles (16 rows each)
#define NGRP  ((NRT + 3) / 4)          // 782 row groups (64 rows)

typedef unsigned short u16;
typedef unsigned int   u32;

typedef __attribute__((ext_vector_type(8))) __bf16 bf16x8;
typedef __attribute__((ext_vector_type(4))) float  f32x4;

// ---------- bf16 storage helpers (fp32 math everywhere) ----------
__device__ __forceinline__ float bf2f(u16 u){ return __uint_as_float(((u32)u)<<16); }
__device__ __forceinline__ float lo16(u32 u){ return __uint_as_float(u<<16); }
__device__ __forceinline__ float hi16(u32 u){ return __uint_as_float(u & 0xffff0000u); }
__device__ __forceinline__ u16 f2bf(float f){
  u32 x = __float_as_uint(f);
  x += 0x7fffu + ((x>>16)&1u);      // round-to-nearest-even
  return (u16)(x>>16);
}
__device__ __forceinline__ float elu_f(float x){ return x>0.f ? x : __expf(x)-1.f; }
__device__ __forceinline__ float lrelu(float x){ return x>0.f ? x : 0.2f*x; }
__device__ __forceinline__ bf16x8 ld_frag(const u16* p){
  uint4 v = *(const uint4*)p;
  return __builtin_bit_cast(bf16x8, v);
}

// ---------- fused prep: mix_w softmax + all weight packing ----------
// frag index space: [0,4096) W0 packs, [4096,20480) W1 packs, [20480,22528) W2cat
__global__ __launch_bounds__(256) void k_prep(
    const float* __restrict__ mix_w, float* __restrict__ wsoft,
    const float* __restrict__ W0, u16* __restrict__ W0p,
    const float* __restrict__ W1, u16* __restrict__ W1p,
    const float* __restrict__ W2, const float* __restrict__ res2, u16* __restrict__ W2p)
{
  int t = blockIdx.x*256 + threadIdx.x;
  if (t < 6){
    float a0 = mix_w[t*2+0], a1 = mix_w[t*2+1];
    float mx = fmaxf(a0,a1);
    float e0 = __expf(a0-mx), e1 = __expf(a1-mx);
    wsoft[t*2+0] = e0/(e0+e1); wsoft[t*2+1] = e1/(e0+e1);
  }
  if (t < 4096){                    // W0: per graph 2048 frags, KB=2, NCOL=256
    int gg = t>>11, fi = t&2047;
    int lane = fi&63, kb = (fi>>6)&1, ct = fi>>7;
    int q = lane>>4, c = lane&15;
    const float* src = W0 + (size_t)gg*64*256;
    u16* o = W0p + (size_t)gg*16384 + (size_t)fi*8;
    #pragma unroll
    for (int j=0;j<8;j++) o[j] = f2bf(src[(size_t)(kb*32+q*8+j)*256 + ct*16 + c]);
  } else if (t < 20480){            // W1: per graph 8192 frags, KB=8, NCOL=256
    int u = t - 4096;
    int gg = u>>13, fi = u&8191;
    int lane = fi&63, kb = (fi>>6)&7, ct = fi>>9;
    int q = lane>>4, c = lane&15;
    const float* src = W1 + (size_t)gg*65536;
    u16* o = W1p + (size_t)gg*65536 + (size_t)fi*8;
    #pragma unroll
    for (int j=0;j<8;j++) o[j] = f2bf(src[(size_t)(kb*32+q*8+j)*256 + ct*16 + c]);
  } else if (t < 22528){            // W2cat: 2048 frags, KB=8, NCOL=64
    int fi = t - 20480;
    int lane = fi&63, kb = (fi>>6)&7, ct = fi>>9;
    int q = lane>>4, c = lane&15;
    int cl = ct*16 + c;
    int i = cl>>5, which = (cl>>4)&1;
    const float* src = which ? res2 : W2;
    u16* o = W2p + (size_t)fi*8;
    #pragma unroll
    for (int j=0;j<8;j++) o[j] = f2bf(src[(size_t)i*4096 + (size_t)(kb*32+q*8+j)*16 + (cl&15)]);
  }
}

// ================= CSR build (both graphs, rebuilt every launch) ===============
__global__ void k_count2(const int* __restrict__ d0, const int* __restrict__ d1,
                         int* __restrict__ cnt2){
  int t = blockIdx.x*256 + threadIdx.x;
  int g = blockIdx.y;
  if (t < EE) atomicAdd(&cnt2[g*NN + (g ? d1[t] : d0[t])], 1);
}

__global__ __launch_bounds__(1024) void k_scan1(const int* __restrict__ cnt2,
                                                int* __restrict__ row2, int* __restrict__ bsum){
  __shared__ int wsum[16];
  int g = blockIdx.y;
  int lane = threadIdx.x & 63, wid = threadIdx.x >> 6;
  int i = blockIdx.x*1024 + threadIdx.x;
  int v = (i < NN) ? cnt2[g*NN + i] : 0;
  int x = v;
  #pragma unroll
  for (int off = 1; off < 64; off <<= 1){
    int y = __shfl_up(x, off, 64);
    if (lane >= off) x += y;
  }
  if (lane == 63) wsum[wid] = x;
  __syncthreads();
  if (wid == 0 && lane < 16){
    int s = wsum[lane];
    #pragma unroll
    for (int off = 1; off < 16; off <<= 1){
      int y = __shfl_up(s, off, 16);
      if (lane >= off) s += y;
    }
    wsum[lane] = s;
  }
  __syncthreads();
  int incl = x + (wid ? wsum[wid-1] : 0);
  if (i < NN) row2[(size_t)g*(NN+1) + i] = incl - v;
  if (threadIdx.x == 1023) bsum[g*NB_SCAN + blockIdx.x] = incl;
}

__global__ __launch_bounds__(128) void k_scan2(const int* __restrict__ bsum, int* __restrict__ boff){
  int g = threadIdx.x >> 6, lane = threadIdx.x & 63;
  int v = (lane < NB_SCAN) ? bsum[g*NB_SCAN + lane] : 0;
  int x = v;
  #pragma unroll
  for (int off = 1; off < 64; off <<= 1){
    int y = __shfl_up(x, off, 64);
    if (lane >= off) x += y;
  }
  if (lane < NB_SCAN) boff[g*NB_SCAN + lane] = x - v;
}

__global__ __launch_bounds__(1024) void k_scan3(int* __restrict__ row2, const int* __restrict__ boff){
  int g = blockIdx.y;
  int i = blockIdx.x*1024 + threadIdx.x;
  if (i < NN) row2[(size_t)g*(NN+1) + i] += boff[g*NB_SCAN + blockIdx.x];
  if (blockIdx.x == 0 && threadIdx.x == 0) row2[(size_t)g*(NN+1) + NN] = EE;
}

__global__ void k_scatter2(const int* __restrict__ s0, const int* __restrict__ d0,
                           const int* __restrict__ s1, const int* __restrict__ d1,
                           const int* __restrict__ row2, int* __restrict__ fill2,
                           int* __restrict__ col2){
  int t = blockIdx.x*256 + threadIdx.x;
  int g = blockIdx.y;
  if (t >= EE) return;
  int d = g ? d1[t] : d0[t];
  int s = g ? s1[t] : s0[t];
  int pos = atomicAdd(&fill2[g*NN + d], 1);
  col2[(size_t)g*EE + row2[(size_t)g*(NN+1) + d] + pos] = s;
}

// ---------- input projection: h0(N,64) = feat_t @ fc_w_t + fc_b_t --------------
__global__ __launch_bounds__(256) void k_in_proj(
    const float* __restrict__ f0, const float* __restrict__ f1,
    const float* __restrict__ w0, const float* __restrict__ b0,
    const float* __restrict__ w1, const float* __restrict__ b1,
    u16* __restrict__ h)
{
  __shared__ float fs[4][128];
  int wv = threadIdx.x>>6, ln = threadIdx.x&63;
  int n = blockIdx.x*4 + wv;                // N divisible by 4
  const float *fr, *W, *B;
  if (n < NN0){ fr = f0 + (size_t)n*128; W=w0; B=b0; }
  else        { fr = f1 + (size_t)(n-NN0)*128; W=w1; B=b1; }
  float2 u = ((const float2*)fr)[ln];
  fs[wv][2*ln]   = u.x;
  fs[wv][2*ln+1] = u.y;
  __syncthreads();
  float acc = B[ln];
  #pragma unroll 8
  for (int k=0;k<128;k++) acc = fmaf(fs[wv][k], W[k*64+ln], acc);
  h[(size_t)n*64 + ln] = f2bf(acc);
}

// ---------- MFMA GEMM, 4 row-tiles x 4 col-tiles per wave ----------------------
// block = 4 waves = 1 row group (64 rows); wave wv = col split (64 cols = head wv)
// grid = ngraph * NGRP; g = blockIdx.x / NGRP
template<int K>
__global__ __launch_bounds__(256) void k_gemm4(
    const u16* __restrict__ A,
    const u16* __restrict__ Bp, size_t bpStride,
    const float* __restrict__ al, const float* __restrict__ ar, int alStride,
    u16* __restrict__ feat, size_t featStride,
    float* __restrict__ el, float* __restrict__ er, size_t elStride)
{
  constexpr int KB = K/32;
  int wv = threadIdx.x>>6, ln = threadIdx.x&63;
  int bid = blockIdx.x;
  int g = bid / NGRP, grp = bid % NGRP;
  int split = wv, q = ln>>4, c = ln&15;
  const u16* Bpg = Bp + (size_t)g*bpStride;
  const float* alg = al + (size_t)g*alStride;
  const float* arg = ar + (size_t)g*alStride;
  u16* featg = feat + (size_t)g*featStride;
  float* elg = el + (size_t)g*elStride;
  float* erg = er + (size_t)g*elStride;

  f32x4 acc[4][4] = {};
  int  tbase = grp*4;
  bool valid[4];
  const u16* Ap[4];
  #pragma unroll
  for (int rt=0; rt<4; rt++){
    int ti = tbase + rt;
    valid[rt] = (ti < NRT);
    if (!valid[rt]) ti = NRT-1;
    Ap[rt] = A + (size_t)(ti*16 + c)*K + q*8;
  }
  const u16* Bbase = Bpg + ((size_t)(split*4)*KB*64 + ln)*8;

  #pragma unroll 2
  for (int kb=0; kb<KB; kb++){
    bf16x8 b[4], a[4];
    #pragma unroll
    for (int ct=0; ct<4; ct++) b[ct] = ld_frag(Bbase + (size_t)(ct*KB + kb)*64*8);
    #pragma unroll
    for (int rt=0; rt<4; rt++) a[rt] = ld_frag(Ap[rt] + kb*32);
    #pragma unroll
    for (int rt=0; rt<4; rt++)
      #pragma unroll
      for (int ct=0; ct<4; ct++)
        acc[rt][ct] = __builtin_amdgcn_mfma_f32_16x16x32_bf16(a[rt], b[ct], acc[rt][ct], 0,0,0);
  }

  // epilogue: head == split; el/er reduce over this wave's 64 cols
  float alv[4], arv[4];
  #pragma unroll
  for (int ct=0;ct<4;ct++){
    int cg = (split*4+ct)*16 + c;
    alv[ct] = alg[cg]; arv[ct] = arg[cg];
  }
  #pragma unroll
  for (int rt=0; rt<4; rt++){
    if (!valid[rt]) continue;          // block-uniform
    int row0 = (tbase+rt)*16;
    #pragma unroll
    for (int j=0;j<4;j++){
      float ep=0.f, rp=0.f;
      #pragma unroll
      for (int ct=0;ct<4;ct++){ ep += acc[rt][ct][j]*alv[ct]; rp += acc[rt][ct][j]*arv[ct]; }
      #pragma unroll
      for (int off=8; off; off>>=1){ ep += __shfl_xor(ep,off,16); rp += __shfl_xor(rp,off,16); }
      int row = row0 + q*4 + j;
      if (c==0){ elg[row*4+split]=ep; erg[row*4+split]=rp; }
      #pragma unroll
      for (int ct=0;ct<4;ct++)
        featg[(size_t)row*256 + (split*4+ct)*16 + c] = f2bf(acc[rt][ct][j]);
    }
  }
}

// ---------- fused dual-graph gather aggregation (256 cols, H=4) ----------------
// single-pass softmax (shift-invariant; |e| small), unroll x4 per graph.
template<int RES>
__global__ __launch_bounds__(256) void k_aggNF(
    const int* __restrict__ row2, const int* __restrict__ col2,
    const u16* __restrict__ feat, size_t featStride,
    const float* __restrict__ el, const float* __restrict__ er, size_t elStride,
    const u16* __restrict__ hres, const float* __restrict__ bias,   // bias [2][256]
    const float* __restrict__ wsoft, int l,
    u16* __restrict__ hout)
{
  int wv = threadIdx.x>>6, ln = threadIdx.x&63;
  int n = blockIdx.x*4 + wv;
  int h = ln>>4;
  int type = (n<NN0)?0:1;
  float rx=0.f, ry=0.f, rz=0.f, rw_=0.f;
  if (RES){
    uint2 r = ((const uint2*)hres)[(size_t)n*64 + ln];
    rx=lo16(r.x); ry=hi16(r.x); rz=lo16(r.y); rw_=hi16(r.y);
  }
  float o0=0.f,o1=0.f,o2=0.f,o3=0.f;
  #pragma unroll
  for (int g=0; g<2; g++){
    const int* rw = row2 + (size_t)g*(NN+1);
    const int* cl = col2 + (size_t)g*EE;
    const uint2* fp = (const uint2*)(feat + (size_t)g*featStride);
    const float* elg = el + (size_t)g*elStride;
    float er_h = (er + (size_t)g*elStride)[n*4+h];
    int beg = rw[n], end = rw[n+1];
    float den = 0.f;
    float a0=0.f,a1=0.f,a2=0.f,a3=0.f;
    int k = beg;
    for (; k+4<=end; k+=4){
      int s0=cl[k], s1=cl[k+1], s2=cl[k+2], s3=cl[k+3];
      float x0 = __expf(lrelu(elg[s0*4+h] + er_h));
      float x1 = __expf(lrelu(elg[s1*4+h] + er_h));
      float x2 = __expf(lrelu(elg[s2*4+h] + er_h));
      float x3 = __expf(lrelu(elg[s3*4+h] + er_h));
      uint2 f0 = fp[(size_t)s0*64 + ln];
      uint2 f1 = fp[(size_t)s1*64 + ln];
      uint2 f2 = fp[(size_t)s2*64 + ln];
      uint2 f3 = fp[(size_t)s3*64 + ln];
      den += (x0+x1) + (x2+x3);
      a0 += x0*lo16(f0.x) + x1*lo16(f1.x) + x2*lo16(f2.x) + x3*lo16(f3.x);
      a1 += x0*hi16(f0.x) + x1*hi16(f1.x) + x2*hi16(f2.x) + x3*hi16(f3.x);
      a2 += x0*lo16(f0.y) + x1*lo16(f1.y) + x2*lo16(f2.y) + x3*lo16(f3.y);
      a3 += x0*hi16(f0.y) + x1*hi16(f1.y) + x2*hi16(f2.y) + x3*hi16(f3.y);
    }
    for (; k<end; k++){
      int s = cl[k];
      float x = __expf(lrelu(elg[s*4+h] + er_h));
      uint2 f = fp[(size_t)s*64 + ln];
      den += x;
      a0 += x*lo16(f.x); a1 += x*hi16(f.x); a2 += x*lo16(f.y); a3 += x*hi16(f.y);
    }
    float inv = (end>beg) ? 1.0f/den : 0.f;
    float4 bv = ((const float4*)(bias + g*256))[ln];
    a0 = a0*inv + bv.x; a1 = a1*inv + bv.y; a2 = a2*inv + bv.z; a3 = a3*inv + bv.w;
    if (RES){ a0 += rx; a1 += ry; a2 += rz; a3 += rw_; }
    float w = wsoft[type*6 + l*2 + g];
    o0 += w*elu_f(a0); o1 += w*elu_f(a1); o2 += w*elu_f(a2); o3 += w*elu_f(a3);
  }
  uint2 o;
  o.x = (u32)f2bf(o0) | ((u32)f2bf(o1)<<16);
  o.y = (u32)f2bf(o2) | ((u32)f2bf(o3)<<16);
  ((uint2*)hout)[(size_t)n*64 + ln] = o;
}

// ---------- fallback: per-graph aggregation with RMW accumulate (round-5) ------
template<int RES>
__global__ __launch_bounds__(256) void k_aggN(
    const int* __restrict__ row, const int* __restrict__ col,
    const u16* __restrict__ feat, const float* __restrict__ el, const float* __restrict__ er,
    const u16* __restrict__ hres, const float* __restrict__ bias,
    const float* __restrict__ wsoft, int l, int i, int first,
    u16* __restrict__ hout)
{
  int wv = threadIdx.x>>6, ln = threadIdx.x&63;
  int n = blockIdx.x*4 + wv;
  int h = ln>>4;
  int beg = row[n], end = row[n+1];
  float er_h = er[n*4+h];
  const uint2* fp = (const uint2*)feat;
  float den = 0.f;
  float a0=0.f,a1=0.f,a2=0.f,a3=0.f;
  int k = beg;
  for (; k+4<=end; k+=4){
    int s0=col[k], s1=col[k+1], s2=col[k+2], s3=col[k+3];
    float x0 = __expf(lrelu(el[s0*4+h] + er_h));
    float x1 = __expf(lrelu(el[s1*4+h] + er_h));
    float x2 = __expf(lrelu(el[s2*4+h] + er_h));
    float x3 = __expf(lrelu(el[s3*4+h] + er_h));
    uint2 f0 = fp[(size_t)s0*64 + ln];
    uint2 f1 = fp[(size_t)s1*64 + ln];
    uint2 f2 = fp[(size_t)s2*64 + ln];
    uint2 f3 = fp[(size_t)s3*64 + ln];
    den += (x0+x1) + (x2+x3);
    a0 += x0*lo16(f0.x) + x1*lo16(f1.x) + x2*lo16(f2.x) + x3*lo16(f3.x);
    a1 += x0*hi16(f0.x) + x1*hi16(f1.x) + x2*hi16(f2.x) + x3*hi16(f3.x);
    a2 += x0*lo16(f0.y) + x1*lo16(f1.y) + x2*lo16(f2.y) + x3*lo16(f3.y);
    a3 += x0*hi16(f0.y) + x1*hi16(f1.y) + x2*hi16(f2.y) + x3*hi16(f3.y);
  }
  for (; k<end; k++){
    int s = col[k];
    float x = __expf(lrelu(el[s*4+h] + er_h));
    uint2 f = fp[(size_t)s*64 + ln];
    den += x;
    a0 += x*lo16(f.x); a1 += x*hi16(f.x); a2 += x*lo16(f.y); a3 += x*hi16(f.y);
  }
  float inv = (end>beg) ? 1.0f/den : 0.f;
  a0 *= inv; a1 *= inv; a2 *= inv; a3 *= inv;
  float4 bv = ((const float4*)bias)[ln];
  a0 += bv.x; a1 += bv.y; a2 += bv.z; a3 += bv.w;
  if (RES){
    uint2 r = ((const uint2*)hres)[(size_t)n*64 + ln];
    a0 += lo16(r.x); a1 += hi16(r.x); a2 += lo16(r.y); a3 += hi16(r.y);
  }
  a0 = elu_f(a0); a1 = elu_f(a1); a2 = elu_f(a2); a3 = elu_f(a3);
  float w = wsoft[((n<NN0)?0:1)*6 + l*2 + i];
  a0 *= w; a1 *= w; a2 *= w; a3 *= w;
  if (!first){
    uint2 p = ((const uint2*)hout)[(size_t)n*64 + ln];
    a0 += lo16(p.x); a1 += hi16(p.x); a2 += lo16(p.y); a3 += hi16(p.y);
  }
  uint2 o;
  o.x = (u32)f2bf(a0) | ((u32)f2bf(a1)<<16);
  o.y = (u32)f2bf(a2) | ((u32)f2bf(a3)<<16);
  ((uint2*)hout)[(size_t)n*64 + ln] = o;
}

// ---------- layer-2 MFMA: A(N,256) @ [W2_0|res2_0|W2_1|res2_1](256,64) ----------
__global__ __launch_bounds__(256) void k_gemm2(
    const u16* __restrict__ A, const u16* __restrict__ Bp,
    const float* __restrict__ al2, const float* __restrict__ ar2,   // [2][16]
    float* __restrict__ feat16, float* __restrict__ resb,           // [2][NN*16]
    float* __restrict__ el2, float* __restrict__ er2)               // [2][NN]
{
  int wv = threadIdx.x>>6, ln = threadIdx.x&63;
  int wt = blockIdx.x*4 + wv;
  if (wt >= NN/16) return;
  int row0 = wt*16;
  int q = ln>>4, c = ln&15;
  f32x4 acc[4] = {};
  const u16* Ap = A + (size_t)(row0 + c)*256 + q*8;
  #pragma unroll
  for (int kb=0; kb<8; kb++){
    bf16x8 a = ld_frag(Ap + kb*32);
    #pragma unroll
    for (int t=0;t<4;t++){
      bf16x8 b = ld_frag(Bp + ((size_t)(t*8 + kb)*64 + ln)*8);
      acc[t] = __builtin_amdgcn_mfma_f32_16x16x32_bf16(a, b, acc[t], 0,0,0);
    }
  }
  #pragma unroll
  for (int i=0;i<2;i++){
    float alv = al2[i*16+c], arv = ar2[i*16+c];
    #pragma unroll
    for (int j=0;j<4;j++){
      float ep = acc[2*i][j]*alv, rp = acc[2*i][j]*arv;
      #pragma unroll
      for (int off=8; off; off>>=1){ ep += __shfl_xor(ep,off,16); rp += __shfl_xor(rp,off,16); }
      if (c==0){
        int row = row0 + q*4 + j;
        el2[(size_t)i*NN + row] = ep; er2[(size_t)i*NN + row] = rp;
      }
    }
    #pragma unroll
    for (int j=0;j<4;j++){
      int row = row0 + q*4 + j;
      feat16[(size_t)i*NN*16 + (size_t)row*16 + c] = acc[2*i][j];
      resb  [(size_t)i*NN*16 + (size_t)row*16 + c] = acc[2*i+1][j];
    }
  }
}

// ---------- layer-2 dual-graph aggregation (16 cols, H=1) + final mix ----------
__global__ __launch_bounds__(256) void k_agg2D(
    const int* __restrict__ row2, const int* __restrict__ col2,
    const float* __restrict__ feat16, const float* __restrict__ el2,
    const float* __restrict__ er2, const float* __restrict__ resb,
    const float* __restrict__ b2, const float* __restrict__ wsoft,
    float* __restrict__ out)
{
  int t = threadIdx.x;
  int nl = t>>4, j = t&15;
  int n = blockIdx.x*16 + nl;
  int type = (n<NN0)?0:1;
  float o = 0.f;
  #pragma unroll
  for (int i=0;i<2;i++){
    const int* rw = row2 + (size_t)i*(NN+1);
    const int* cl = col2 + (size_t)i*EE;
    const float* f  = feat16 + (size_t)i*NN*16;
    const float* eli= el2 + (size_t)i*NN;
    float ern = er2[(size_t)i*NN + n];
    int beg = rw[n], end = rw[n+1];
    float den = 0.f, acc = 0.f;
    int k = beg;
    for (; k+4<=end; k+=4){
      int s0=cl[k], s1=cl[k+1], s2=cl[k+2], s3=cl[k+3];
      float x0 = __expf(lrelu(eli[s0] + ern));
      float x1 = __expf(lrelu(eli[s1] + ern));
      float x2 = __expf(lrelu(eli[s2] + ern));
      float x3 = __expf(lrelu(eli[s3] + ern));
      float v0 = f[(size_t)s0*16 + j];
      float v1 = f[(size_t)s1*16 + j];
      float v2 = f[(size_t)s2*16 + j];
      float v3 = f[(size_t)s3*16 + j];
      den += (x0+x1) + (x2+x3);
      acc += x0*v0 + x1*v1 + x2*v2 + x3*v3;
    }
    for (; k<end; k++){
      int s = cl[k];
      float x = __expf(lrelu(eli[s] + ern));
      den += x;
      acc = fmaf(x, f[(size_t)s*16 + j], acc);
    }
    float inv = (end>beg) ? 1.0f/den : 0.f;
    float oi = acc*inv + b2[i*16+j] + resb[(size_t)i*NN*16 + (size_t)n*16 + j];
    o += oi * wsoft[type*6 + 4 + i];
  }
  out[(size_t)n*16 + j] = o;
}

extern "C" void kernel_launch(void* const* d_in, const int* in_sizes, int n_in,
                              void* d_out, int out_size, void* d_ws, size_t ws_size,
                              hipStream_t stream)
{
  const float* features0 = (const float*)d_in[0];
  const float* features1 = (const float*)d_in[1];
  const float* fc_w0 = (const float*)d_in[2];
  const float* fc_b0 = (const float*)d_in[3];
  const float* fc_w1 = (const float*)d_in[4];
  const float* fc_b1 = (const float*)d_in[5];
  const float* mix_w = (const float*)d_in[6];
  const float* W0  = (const float*)d_in[7];
  const float* al0 = (const float*)d_in[8];
  const float* ar0 = (const float*)d_in[9];
  const float* b0  = (const float*)d_in[10];
  const float* W1  = (const float*)d_in[11];
  const float* al1 = (const float*)d_in[12];
  const float* ar1 = (const float*)d_in[13];
  const float* b1  = (const float*)d_in[14];
  const float* W2  = (const float*)d_in[15];
  const float* al2 = (const float*)d_in[16];
  const float* ar2 = (const float*)d_in[17];
  const float* b2  = (const float*)d_in[18];
  const float* res2= (const float*)d_in[19];
  const int* src[2] = {(const int*)d_in[20], (const int*)d_in[22]};
  const int* dst[2] = {(const int*)d_in[21], (const int*)d_in[23]};
  (void)in_sizes; (void)n_in; (void)out_size;

  char* ws = (char*)d_ws;
  size_t off = 0;
  auto alloc = [&](size_t bytes)->char*{
    char* p = ws + off; off += (bytes + 255) & ~(size_t)255; return p;
  };
  // common buffers
  float* wsoft = (float*)alloc(64*4);
  u16*   W0p   = (u16*)  alloc((size_t)2*64*256*2);
  u16*   W1p   = (u16*)  alloc((size_t)2*256*256*2);
  u16*   W2p   = (u16*)  alloc((size_t)256*64*2);
  int*   row2  = (int*)  alloc((size_t)2*(NN+1)*4);
  int*   col2  = (int*)  alloc((size_t)2*EE*4);
  int*   zeros = (int*)  alloc((size_t)4*NN*4);       // cnt2 + fill2, one memset
  int*   cnt2  = zeros;
  int*   fill2 = zeros + 2*NN;
  int*   bsum  = (int*)alloc((size_t)2*NB_SCAN*4);
  int*   boff  = (int*)alloc((size_t)2*NB_SCAN*4);
  u16*   h0    = (u16*)alloc((size_t)NN*64*2);
  u16*   h1    = (u16*)alloc((size_t)NN*256*2);
  u16*   h2    = (u16*)alloc((size_t)NN*256*2);
  float* elA   = (float*)alloc((size_t)2*NN*4*4);
  float* erA   = (float*)alloc((size_t)2*NN*4*4);
  // region D: feat buffers (1 or 2 graphs); layer-2 outputs alias it afterwards
  size_t featBytes1 = (size_t)NN*256*2;
  size_t off_D = off;
  bool fused = (ws_size >= off_D + 2*featBytes1 + (16<<20));  // headroom
  u16* featD = (u16*)alloc(fused ? 2*featBytes1 : featBytes1);
  // layer-2 aliases into region D (feat dead by then): 6.4+6.4+0.2+0.2 MB < 25.6 MB
  float* feat16 = (float*)(ws + off_D);
  float* resb   = feat16 + (size_t)2*NN*16;
  float* el2    = resb   + (size_t)2*NN*16;
  float* er2    = el2    + (size_t)2*NN;

  // 1. prep: mixw + pack all weights
  k_prep<<<(22528+255)/256,256,0,stream>>>(mix_w, wsoft, W0, W0p, W1, W1p, W2, res2, W2p);

  // 2. CSR build, both graphs
  hipMemsetAsync(zeros, 0, (size_t)4*NN*4, stream);
  {
    dim3 gE((EE+255)/256, 2), gS(NB_SCAN, 2);
    k_count2 <<<gE,256,0,stream>>>(dst[0], dst[1], cnt2);
    k_scan1  <<<gS,1024,0,stream>>>(cnt2, row2, bsum);
    k_scan2  <<<1,128,0,stream>>>(bsum, boff);
    k_scan3  <<<gS,1024,0,stream>>>(row2, boff);
    k_scatter2<<<gE,256,0,stream>>>(src[0], dst[0], src[1], dst[1], row2, fill2, col2);
  }

  // 3. input projection
  k_in_proj<<<NN/4,256,0,stream>>>(features0, features1, fc_w0, fc_b0, fc_w1, fc_b1, h0);

  if (fused){
    // layer 0
    k_gemm4<64><<<2*NGRP,256,0,stream>>>(h0, W0p, (size_t)64*256, al0, ar0, 256,
                                         featD, featBytes1/2, elA, erA, (size_t)NN*4);
    k_aggNF<0><<<NN/4,256,0,stream>>>(row2, col2, featD, featBytes1/2, elA, erA, (size_t)NN*4,
                                      (const u16*)nullptr, b0, wsoft, 0, h1);
    // layer 1
    k_gemm4<256><<<2*NGRP,256,0,stream>>>(h1, W1p, (size_t)256*256, al1, ar1, 256,
                                          featD, featBytes1/2, elA, erA, (size_t)NN*4);
    k_aggNF<1><<<NN/4,256,0,stream>>>(row2, col2, featD, featBytes1/2, elA, erA, (size_t)NN*4,
                                      h1, b1, wsoft, 1, h2);
  } else {
    // per-graph fallback (round-5 structure, new GEMM)
    for (int i=0;i<2;i++){
      k_gemm4<64><<<NGRP,256,0,stream>>>(h0, W0p+(size_t)i*64*256, 0, al0+i*256, ar0+i*256, 0,
                                         featD, 0, elA, erA, 0);
      k_aggN<0><<<NN/4,256,0,stream>>>(row2+(size_t)i*(NN+1), col2+(size_t)i*EE, featD, elA, erA,
                                       (const u16*)nullptr, b0+i*256, wsoft, 0, i, (i==0)?1:0, h1);
    }
    for (int i=0;i<2;i++){
      k_gemm4<256><<<NGRP,256,0,stream>>>(h1, W1p+(size_t)i*256*256, 0, al1+i*256, ar1+i*256, 0,
                                          featD, 0, elA, erA, 0);
      k_aggN<1><<<NN/4,256,0,stream>>>(row2+(size_t)i*(NN+1), col2+(size_t)i*EE, featD, elA, erA,
                                       h1, b1+i*256, wsoft, 1, i, (i==0)?1:0, h2);
    }
  }

  // layer 2 (both graphs fused; outputs alias region D — feat is dead here)
  k_gemm2<<<(NN/16+3)/4,256,0,stream>>>(h2, W2p, al2, ar2, feat16, resb, el2, er2);
  k_agg2D<<<NN/16,256,0,stream>>>(row2, col2, feat16, el2, er2, resb, b2, wsoft, (float*)d_out);
}

// Round 7
// 465.932 us; speedup vs baseline: 3.9254x; 1.0663x over previous
//
#include <hip/hip_runtime.h>
#include <hip/hip_bf16.h>

// Problem constants (match reference)
#define NN   50000   // N0+N1
#define NN0  30000
#define EE   400000
#define NB_SCAN ((NN + 1023) / 1024)   // 49
#define NRT   3125                     // row tiles (16 rows each)
#define NGRP  ((NRT + 3) / 4)          // 782 row groups (64 rows)
#define NT0   1875                     // type-0 row tiles (30000/16, exact)

typedef unsigned short u16;
typedef unsigned int   u32;

typedef __attribute__((ext_vector_type(8))) __bf16 bf16x8;
typedef __attribute__((ext_vector_type(4))) float  f32x4;

// ---------- bf16 storage helpers (fp32 math everywhere) ----------
__device__ __forceinline__ float bf2f(u16 u){ return __uint_as_float(((u32)u)<<16); }
__device__ __forceinline__ float lo16(u32 u){ return __uint_as_float(u<<16); }
__device__ __forceinline__ float hi16(u32 u){ return __uint_as_float(u & 0xffff0000u); }
__device__ __forceinline__ u16 f2bf(float f){
  u32 x = __float_as_uint(f);
  x += 0x7fffu + ((x>>16)&1u);      // round-to-nearest-even
  return (u16)(x>>16);
}
__device__ __forceinline__ float elu_f(float x){ return x>0.f ? x : __expf(x)-1.f; }
__device__ __forceinline__ float lrelu(float x){ return x>0.f ? x : 0.2f*x; }
__device__ __forceinline__ bf16x8 ld_frag(const u16* p){
  uint4 v = *(const uint4*)p;
  return __builtin_bit_cast(bf16x8, v);
}
__device__ __forceinline__ bf16x8 cvt8(const float* p){   // 8 f32 -> bf16x8
  float4 u = ((const float4*)p)[0];
  float4 v = ((const float4*)p)[1];
  u32 w0 = (u32)f2bf(u.x) | ((u32)f2bf(u.y)<<16);
  u32 w1 = (u32)f2bf(u.z) | ((u32)f2bf(u.w)<<16);
  u32 w2 = (u32)f2bf(v.x) | ((u32)f2bf(v.y)<<16);
  u32 w3 = (u32)f2bf(v.z) | ((u32)f2bf(v.w)<<16);
  uint4 r{w0,w1,w2,w3};
  return __builtin_bit_cast(bf16x8, r);
}

// ---------- fused prep: mixw softmax + all weight packing + V = [W*al | W*ar] --
// thread space: [0,4096) W0p | [4096,20480) W1p | [20480,22528) W2p
//               [22528,24576) Fp (fc_w) | [24576,25600) Vp elements
__global__ __launch_bounds__(256) void k_prep(
    const float* __restrict__ mix_w, float* __restrict__ wsoft,
    const float* __restrict__ W0, u16* __restrict__ W0p,
    const float* __restrict__ W1, u16* __restrict__ W1p,
    const float* __restrict__ W2, const float* __restrict__ res2, u16* __restrict__ W2p,
    const float* __restrict__ fcw0, const float* __restrict__ fcw1, u16* __restrict__ Fp,
    const float* __restrict__ al0, const float* __restrict__ ar0, u16* __restrict__ Vp)
{
  int t = blockIdx.x*256 + threadIdx.x;
  if (t < 6){
    float a0 = mix_w[t*2+0], a1 = mix_w[t*2+1];
    float mx = fmaxf(a0,a1);
    float e0 = __expf(a0-mx), e1 = __expf(a1-mx);
    wsoft[t*2+0] = e0/(e0+e1); wsoft[t*2+1] = e1/(e0+e1);
  }
  if (t < 4096){                    // W0: per graph 2048 frags, KB=2, NCOL=256
    int gg = t>>11, fi = t&2047;
    int lane = fi&63, kb = (fi>>6)&1, ct = fi>>7;
    int q = lane>>4, c = lane&15;
    const float* src = W0 + (size_t)gg*16384;
    u16* o = W0p + (size_t)gg*16384 + (size_t)fi*8;
    #pragma unroll
    for (int j=0;j<8;j++) o[j] = f2bf(src[(size_t)(kb*32+q*8+j)*256 + ct*16 + c]);
  } else if (t < 20480){            // W1: per graph 8192 frags, KB=8, NCOL=256
    int u = t - 4096;
    int gg = u>>13, fi = u&8191;
    int lane = fi&63, kb = (fi>>6)&7, ct = fi>>9;
    int q = lane>>4, c = lane&15;
    const float* src = W1 + (size_t)gg*65536;
    u16* o = W1p + (size_t)gg*65536 + (size_t)fi*8;
    #pragma unroll
    for (int j=0;j<8;j++) o[j] = f2bf(src[(size_t)(kb*32+q*8+j)*256 + ct*16 + c]);
  } else if (t < 22528){            // W2cat: 2048 frags, KB=8, NCOL=64
    int fi = t - 20480;
    int lane = fi&63, kb = (fi>>6)&7, ct = fi>>9;
    int q = lane>>4, c = lane&15;
    int cl = ct*16 + c;
    int i = cl>>5, which = (cl>>4)&1;
    const float* src = which ? res2 : W2;
    u16* o = W2p + (size_t)fi*8;
    #pragma unroll
    for (int j=0;j<8;j++) o[j] = f2bf(src[(size_t)i*4096 + (size_t)(kb*32+q*8+j)*16 + (cl&15)]);
  } else if (t < 24576){            // fc_w: per type 1024 frags, KB=4, NCOL=64
    int u = t - 22528;
    int tt = u>>10, fi = u&1023;
    int lane = fi&63, kb = (fi>>6)&3, ct = fi>>8;
    int q = lane>>4, c = lane&15;
    const float* src = tt ? fcw1 : fcw0;
    u16* o = Fp + (size_t)tt*8192 + (size_t)fi*8;
    #pragma unroll
    for (int j=0;j<8;j++) o[j] = f2bf(src[(size_t)(kb*32+q*8+j)*64 + ct*16 + c]);
  } else if (t < 25600){            // Vp: 64x16, KB=2; col c: which=c>>3, g=(c>>2)&1, h=c&3
    int u = t - 24576;              // one element each (fi, j)
    int fi = u>>3, j = u&7;
    int lane = fi&63, kb = fi>>6;
    int q = lane>>4, c = lane&15;
    int k = kb*32 + q*8 + j;
    int which = c>>3, g=(c>>2)&1, h=c&3;
    const float* sel = (which ? ar0 : al0) + (size_t)(g*4+h)*64;
    const float* Wrow = W0 + (size_t)g*16384 + (size_t)k*256 + h*64;
    float s=0.f;
    #pragma unroll 8
    for (int d=0;d<64;d++) s = fmaf(Wrow[d], sel[d], s);
    Vp[(size_t)fi*8 + j] = f2bf(s);
  }
}

// ================= CSR build (both graphs, rebuilt every launch) ===============
__global__ void k_count2(const int* __restrict__ d0, const int* __restrict__ d1,
                         int* __restrict__ cnt2){
  int t = blockIdx.x*256 + threadIdx.x;
  int g = blockIdx.y;
  if (t < EE) atomicAdd(&cnt2[g*NN + (g ? d1[t] : d0[t])], 1);
}

__global__ __launch_bounds__(1024) void k_scan1(const int* __restrict__ cnt2,
                                                int* __restrict__ row2, int* __restrict__ bsum){
  __shared__ int wsum[16];
  int g = blockIdx.y;
  int lane = threadIdx.x & 63, wid = threadIdx.x >> 6;
  int i = blockIdx.x*1024 + threadIdx.x;
  int v = (i < NN) ? cnt2[g*NN + i] : 0;
  int x = v;
  #pragma unroll
  for (int off = 1; off < 64; off <<= 1){
    int y = __shfl_up(x, off, 64);
    if (lane >= off) x += y;
  }
  if (lane == 63) wsum[wid] = x;
  __syncthreads();
  if (wid == 0 && lane < 16){
    int s = wsum[lane];
    #pragma unroll
    for (int off = 1; off < 16; off <<= 1){
      int y = __shfl_up(s, off, 16);
      if (lane >= off) s += y;
    }
    wsum[lane] = s;
  }
  __syncthreads();
  int incl = x + (wid ? wsum[wid-1] : 0);
  if (i < NN) row2[(size_t)g*(NN+1) + i] = incl - v;
  if (threadIdx.x == 1023) bsum[g*NB_SCAN + blockIdx.x] = incl;
}

__global__ __launch_bounds__(128) void k_scan2(const int* __restrict__ bsum, int* __restrict__ boff){
  int g = threadIdx.x >> 6, lane = threadIdx.x & 63;
  int v = (lane < NB_SCAN) ? bsum[g*NB_SCAN + lane] : 0;
  int x = v;
  #pragma unroll
  for (int off = 1; off < 64; off <<= 1){
    int y = __shfl_up(x, off, 64);
    if (lane >= off) x += y;
  }
  if (lane < NB_SCAN) boff[g*NB_SCAN + lane] = x - v;
}

__global__ __launch_bounds__(1024) void k_scan3(int* __restrict__ row2, const int* __restrict__ boff){
  int g = blockIdx.y;
  int i = blockIdx.x*1024 + threadIdx.x;
  if (i < NN) row2[(size_t)g*(NN+1) + i] += boff[g*NB_SCAN + blockIdx.x];
  if (blockIdx.x == 0 && threadIdx.x == 0) row2[(size_t)g*(NN+1) + NN] = EE;
}

__global__ void k_scatter2(const int* __restrict__ s0, const int* __restrict__ d0,
                           const int* __restrict__ s1, const int* __restrict__ d1,
                           const int* __restrict__ row2, int* __restrict__ fill2,
                           int* __restrict__ col2){
  int t = blockIdx.x*256 + threadIdx.x;
  int g = blockIdx.y;
  if (t >= EE) return;
  int d = g ? d1[t] : d0[t];
  int s = g ? s1[t] : s0[t];
  int pos = atomicAdd(&fill2[g*NN + d], 1);
  col2[(size_t)g*EE + row2[(size_t)g*(NN+1) + d] + pos] = s;
}

// ---------- input projection (MFMA): h0(N,64) = feat_t @ fc_w_t + fc_b_t -------
// tiles never straddle the type boundary (30000 = 1875*16)
__global__ __launch_bounds__(256) void k_inproj_m(
    const float* __restrict__ f0, const float* __restrict__ f1,
    const u16* __restrict__ Fp, const float* __restrict__ fb0, const float* __restrict__ fb1,
    u16* __restrict__ h0)
{
  int wv = threadIdx.x>>6, ln = threadIdx.x&63;
  int ti = blockIdx.x*4 + wv;
  if (ti >= NRT) return;
  int q = ln>>4, c = ln&15;
  int type = (ti < NT0) ? 0 : 1;
  const float* F = type ? f1 : f0;
  int rbase = type ? (ti*16 - NN0) : ti*16;
  const u16* Bg = Fp + (size_t)type*8192;
  const float* bb = type ? fb1 : fb0;
  f32x4 acc[4] = {};
  const float* Ap = F + (size_t)(rbase + c)*128;
  #pragma unroll
  for (int kb=0; kb<4; kb++){
    bf16x8 a = cvt8(Ap + kb*32 + q*8);
    #pragma unroll
    for (int ct=0; ct<4; ct++){
      bf16x8 b = ld_frag(Bg + ((size_t)(ct*4+kb)*64 + ln)*8);
      acc[ct] = __builtin_amdgcn_mfma_f32_16x16x32_bf16(a, b, acc[ct], 0,0,0);
    }
  }
  #pragma unroll
  for (int ct=0; ct<4; ct++){
    float bv = bb[ct*16+c];
    #pragma unroll
    for (int j=0;j<4;j++){
      int row = ti*16 + q*4 + j;
      h0[(size_t)row*64 + ct*16 + c] = f2bf(acc[ct][j] + bv);
    }
  }
}

// ---------- layer-0 el/er: (N,64) @ Vp(64,16); c: which=c>>3, g=(c>>2)&1, h=c&3 -
__global__ __launch_bounds__(256) void k_eler0(
    const u16* __restrict__ h0, const u16* __restrict__ Vp,
    float* __restrict__ elA, float* __restrict__ erA)
{
  int wv = threadIdx.x>>6, ln = threadIdx.x&63;
  int ti = blockIdx.x*4 + wv;
  if (ti >= NRT) return;
  int q = ln>>4, c = ln&15;
  f32x4 acc = {};
  const u16* Ap = h0 + (size_t)(ti*16 + c)*64 + q*8;
  #pragma unroll
  for (int kb=0; kb<2; kb++){
    bf16x8 a = ld_frag(Ap + kb*32);
    bf16x8 b = ld_frag(Vp + ((size_t)(kb*64 + ln))*8);
    acc = __builtin_amdgcn_mfma_f32_16x16x32_bf16(a, b, acc, 0,0,0);
  }
  int which = c>>3, g = (c>>2)&1, h = c&3;
  float* dst = (which ? erA : elA) + (size_t)g*NN*4;
  #pragma unroll
  for (int j=0;j<4;j++){
    int row = ti*16 + q*4 + j;
    dst[row*4 + h] = acc[j];
  }
}

// ---------- layer-0 aggregation: gather h0 (64 cols!), per-head alpha ----------
// agg_g[n, h, k] = sum_e alpha_g,h(e) * h0[src_e, k];  h0 is 6.4 MB -> L2-resident
__global__ __launch_bounds__(256) void k_agg0(
    const int* __restrict__ row2, const int* __restrict__ col2,
    const u16* __restrict__ h0,
    const float* __restrict__ elA, const float* __restrict__ erA,
    u16* __restrict__ aggB, size_t aggStride)
{
  int wv = threadIdx.x>>6, ln = threadIdx.x&63;
  int n = blockIdx.x*4 + wv;
  #pragma unroll
  for (int g=0; g<2; g++){
    const int* rw = row2 + (size_t)g*(NN+1);
    const int* cl = col2 + (size_t)g*EE;
    const float* elg = elA + (size_t)g*NN*4;
    float4 er4 = ((const float4*)(erA + (size_t)g*NN*4))[n];
    int beg = rw[n], end = rw[n+1];
    float d0=0.f,d1=0.f,d2=0.f,d3=0.f;
    float a0=0.f,a1=0.f,a2=0.f,a3=0.f;
    int k = beg;
    for (; k+2<=end; k+=2){
      int s0 = cl[k], s1 = cl[k+1];
      float4 e0 = ((const float4*)elg)[s0];
      float4 e1 = ((const float4*)elg)[s1];
      float v0 = bf2f(h0[(size_t)s0*64 + ln]);
      float v1 = bf2f(h0[(size_t)s1*64 + ln]);
      float x00=__expf(lrelu(e0.x+er4.x)), x01=__expf(lrelu(e0.y+er4.y));
      float x02=__expf(lrelu(e0.z+er4.z)), x03=__expf(lrelu(e0.w+er4.w));
      float x10=__expf(lrelu(e1.x+er4.x)), x11=__expf(lrelu(e1.y+er4.y));
      float x12=__expf(lrelu(e1.z+er4.z)), x13=__expf(lrelu(e1.w+er4.w));
      d0 += x00+x10; d1 += x01+x11; d2 += x02+x12; d3 += x03+x13;
      a0 += x00*v0 + x10*v1; a1 += x01*v0 + x11*v1;
      a2 += x02*v0 + x12*v1; a3 += x03*v0 + x13*v1;
    }
    for (; k<end; k++){
      int s = cl[k];
      float4 e0 = ((const float4*)elg)[s];
      float v = bf2f(h0[(size_t)s*64 + ln]);
      float x0=__expf(lrelu(e0.x+er4.x)), x1=__expf(lrelu(e0.y+er4.y));
      float x2=__expf(lrelu(e0.z+er4.z)), x3=__expf(lrelu(e0.w+er4.w));
      d0+=x0; d1+=x1; d2+=x2; d3+=x3;
      a0+=x0*v; a1+=x1*v; a2+=x2*v; a3+=x3*v;
    }
    bool has = (end > beg);
    a0 = has ? a0/d0 : 0.f; a1 = has ? a1/d1 : 0.f;
    a2 = has ? a2/d2 : 0.f; a3 = has ? a3/d3 : 0.f;
    u16* og = aggB + (size_t)g*aggStride + (size_t)n*256 + ln;
    og[0]   = f2bf(a0); og[64]  = f2bf(a1);
    og[128] = f2bf(a2); og[192] = f2bf(a3);
  }
}

// ---------- layer-0 head GEMM: out[n,h*64+d] = ELU(agg_g[n,h,:]@W0_g[:,h,:]+b) mixed
__global__ __launch_bounds__(256) void k_head0(
    const u16* __restrict__ aggB, size_t aggStride,
    const u16* __restrict__ W0p, const float* __restrict__ b0,
    const float* __restrict__ wsoft, u16* __restrict__ h1)
{
  int wv = threadIdx.x>>6, ln = threadIdx.x&63;
  int ti = blockIdx.x*4 + wv;
  if (ti >= NRT) return;
  int q = ln>>4, c = ln&15;
  int type = (ti < NT0) ? 0 : 1;
  float wg0 = wsoft[type*6 + 0];
  float wg1 = wsoft[type*6 + 1];
  for (int h=0; h<4; h++){
    f32x4 acc[2][4] = {};
    #pragma unroll
    for (int g=0; g<2; g++){
      const u16* Ap = aggB + (size_t)g*aggStride + (size_t)(ti*16 + c)*256 + h*64 + q*8;
      const u16* Bg = W0p + (size_t)g*16384;
      #pragma unroll
      for (int kb=0; kb<2; kb++){
        bf16x8 a = ld_frag(Ap + kb*32);
        #pragma unroll
        for (int ct=0; ct<4; ct++){
          int ctg = h*4 + ct;
          bf16x8 b = ld_frag(Bg + ((size_t)(ctg*2 + kb)*64 + ln)*8);
          acc[g][ct] = __builtin_amdgcn_mfma_f32_16x16x32_bf16(a, b, acc[g][ct], 0,0,0);
        }
      }
    }
    #pragma unroll
    for (int ct=0; ct<4; ct++){
      int colg = h*64 + ct*16 + c;
      float bb0 = b0[colg], bb1 = b0[256 + colg];
      #pragma unroll
      for (int j=0;j<4;j++){
        int row = ti*16 + q*4 + j;
        float o = wg0*elu_f(acc[0][ct][j] + bb0) + wg1*elu_f(acc[1][ct][j] + bb1);
        h1[(size_t)row*256 + colg] = f2bf(o);
      }
    }
  }
}

// ---------- MFMA GEMM, 4 row-tiles x 4 col-tiles per wave (layer 1) ------------
template<int K>
__global__ __launch_bounds__(256) void k_gemm4(
    const u16* __restrict__ A,
    const u16* __restrict__ Bp, size_t bpStride,
    const float* __restrict__ al, const float* __restrict__ ar, int alStride,
    u16* __restrict__ feat, size_t featStride,
    float* __restrict__ el, float* __restrict__ er, size_t elStride)
{
  constexpr int KB = K/32;
  int wv = threadIdx.x>>6, ln = threadIdx.x&63;
  int bid = blockIdx.x;
  int g = bid / NGRP, grp = bid % NGRP;
  int split = wv, q = ln>>4, c = ln&15;
  const u16* Bpg = Bp + (size_t)g*bpStride;
  const float* alg = al + (size_t)g*alStride;
  const float* arg = ar + (size_t)g*alStride;
  u16* featg = feat + (size_t)g*featStride;
  float* elg = el + (size_t)g*elStride;
  float* erg = er + (size_t)g*elStride;

  f32x4 acc[4][4] = {};
  int  tbase = grp*4;
  bool valid[4];
  const u16* Ap[4];
  #pragma unroll
  for (int rt=0; rt<4; rt++){
    int ti = tbase + rt;
    valid[rt] = (ti < NRT);
    if (!valid[rt]) ti = NRT-1;
    Ap[rt] = A + (size_t)(ti*16 + c)*K + q*8;
  }
  const u16* Bbase = Bpg + ((size_t)(split*4)*KB*64 + ln)*8;

  #pragma unroll 2
  for (int kb=0; kb<KB; kb++){
    bf16x8 b[4], a[4];
    #pragma unroll
    for (int ct=0; ct<4; ct++) b[ct] = ld_frag(Bbase + (size_t)(ct*KB + kb)*64*8);
    #pragma unroll
    for (int rt=0; rt<4; rt++) a[rt] = ld_frag(Ap[rt] + kb*32);
    #pragma unroll
    for (int rt=0; rt<4; rt++)
      #pragma unroll
      for (int ct=0; ct<4; ct++)
        acc[rt][ct] = __builtin_amdgcn_mfma_f32_16x16x32_bf16(a[rt], b[ct], acc[rt][ct], 0,0,0);
  }

  float alv[4], arv[4];
  #pragma unroll
  for (int ct=0;ct<4;ct++){
    int cg = (split*4+ct)*16 + c;
    alv[ct] = alg[cg]; arv[ct] = arg[cg];
  }
  #pragma unroll
  for (int rt=0; rt<4; rt++){
    if (!valid[rt]) continue;
    int row0 = (tbase+rt)*16;
    #pragma unroll
    for (int j=0;j<4;j++){
      float ep=0.f, rp=0.f;
      #pragma unroll
      for (int ct=0;ct<4;ct++){ ep += acc[rt][ct][j]*alv[ct]; rp += acc[rt][ct][j]*arv[ct]; }
      #pragma unroll
      for (int off=8; off; off>>=1){ ep += __shfl_xor(ep,off,16); rp += __shfl_xor(rp,off,16); }
      int row = row0 + q*4 + j;
      if (c==0){ elg[row*4+split]=ep; erg[row*4+split]=rp; }
      #pragma unroll
      for (int ct=0;ct<4;ct++)
        featg[(size_t)row*256 + (split*4+ct)*16 + c] = f2bf(acc[rt][ct][j]);
    }
  }
}

// ---------- fused dual-graph gather aggregation (256 cols, H=4), layer 1 -------
template<int RES>
__global__ __launch_bounds__(256) void k_aggNF(
    const int* __restrict__ row2, const int* __restrict__ col2,
    const u16* __restrict__ feat, size_t featStride,
    const float* __restrict__ el, const float* __restrict__ er, size_t elStride,
    const u16* __restrict__ hres, const float* __restrict__ bias,
    const float* __restrict__ wsoft, int l,
    u16* __restrict__ hout)
{
  int wv = threadIdx.x>>6, ln = threadIdx.x&63;
  int n = blockIdx.x*4 + wv;
  int h = ln>>4;
  int type = (n<NN0)?0:1;
  float rx=0.f, ry=0.f, rz=0.f, rw_=0.f;
  if (RES){
    uint2 r = ((const uint2*)hres)[(size_t)n*64 + ln];
    rx=lo16(r.x); ry=hi16(r.x); rz=lo16(r.y); rw_=hi16(r.y);
  }
  float o0=0.f,o1=0.f,o2=0.f,o3=0.f;
  #pragma unroll
  for (int g=0; g<2; g++){
    const int* rw = row2 + (size_t)g*(NN+1);
    const int* cl = col2 + (size_t)g*EE;
    const uint2* fp = (const uint2*)(feat + (size_t)g*featStride);
    const float* elg = el + (size_t)g*elStride;
    float er_h = (er + (size_t)g*elStride)[n*4+h];
    int beg = rw[n], end = rw[n+1];
    float den = 0.f;
    float a0=0.f,a1=0.f,a2=0.f,a3=0.f;
    int k = beg;
    for (; k+4<=end; k+=4){
      int s0=cl[k], s1=cl[k+1], s2=cl[k+2], s3=cl[k+3];
      float x0 = __expf(lrelu(elg[s0*4+h] + er_h));
      float x1 = __expf(lrelu(elg[s1*4+h] + er_h));
      float x2 = __expf(lrelu(elg[s2*4+h] + er_h));
      float x3 = __expf(lrelu(elg[s3*4+h] + er_h));
      uint2 f0 = fp[(size_t)s0*64 + ln];
      uint2 f1 = fp[(size_t)s1*64 + ln];
      uint2 f2 = fp[(size_t)s2*64 + ln];
      uint2 f3 = fp[(size_t)s3*64 + ln];
      den += (x0+x1) + (x2+x3);
      a0 += x0*lo16(f0.x) + x1*lo16(f1.x) + x2*lo16(f2.x) + x3*lo16(f3.x);
      a1 += x0*hi16(f0.x) + x1*hi16(f1.x) + x2*hi16(f2.x) + x3*hi16(f3.x);
      a2 += x0*lo16(f0.y) + x1*lo16(f1.y) + x2*lo16(f2.y) + x3*lo16(f3.y);
      a3 += x0*hi16(f0.y) + x1*hi16(f1.y) + x2*hi16(f2.y) + x3*hi16(f3.y);
    }
    for (; k<end; k++){
      int s = cl[k];
      float x = __expf(lrelu(elg[s*4+h] + er_h));
      uint2 f = fp[(size_t)s*64 + ln];
      den += x;
      a0 += x*lo16(f.x); a1 += x*hi16(f.x); a2 += x*lo16(f.y); a3 += x*hi16(f.y);
    }
    float inv = (end>beg) ? 1.0f/den : 0.f;
    float4 bv = ((const float4*)(bias + g*256))[ln];
    a0 = a0*inv + bv.x; a1 = a1*inv + bv.y; a2 = a2*inv + bv.z; a3 = a3*inv + bv.w;
    if (RES){ a0 += rx; a1 += ry; a2 += rz; a3 += rw_; }
    float w = wsoft[type*6 + l*2 + g];
    o0 += w*elu_f(a0); o1 += w*elu_f(a1); o2 += w*elu_f(a2); o3 += w*elu_f(a3);
  }
  uint2 o;
  o.x = (u32)f2bf(o0) | ((u32)f2bf(o1)<<16);
  o.y = (u32)f2bf(o2) | ((u32)f2bf(o3)<<16);
  ((uint2*)hout)[(size_t)n*64 + ln] = o;
}

// ---------- layer-2 MFMA: A(N,256) @ [W2_0|res2_0|W2_1|res2_1](256,64) ----------
__global__ __launch_bounds__(256) void k_gemm2(
    const u16* __restrict__ A, const u16* __restrict__ Bp,
    const float* __restrict__ al2, const float* __restrict__ ar2,
    float* __restrict__ feat16, float* __restrict__ resb,
    float* __restrict__ el2, float* __restrict__ er2)
{
  int wv = threadIdx.x>>6, ln = threadIdx.x&63;
  int wt = blockIdx.x*4 + wv;
  if (wt >= NRT) return;
  int row0 = wt*16;
  int q = ln>>4, c = ln&15;
  f32x4 acc[4] = {};
  const u16* Ap = A + (size_t)(row0 + c)*256 + q*8;
  #pragma unroll
  for (int kb=0; kb<8; kb++){
    bf16x8 a = ld_frag(Ap + kb*32);
    #pragma unroll
    for (int t=0;t<4;t++){
      bf16x8 b = ld_frag(Bp + ((size_t)(t*8 + kb)*64 + ln)*8);
      acc[t] = __builtin_amdgcn_mfma_f32_16x16x32_bf16(a, b, acc[t], 0,0,0);
    }
  }
  #pragma unroll
  for (int i=0;i<2;i++){
    float alv = al2[i*16+c], arv = ar2[i*16+c];
    #pragma unroll
    for (int j=0;j<4;j++){
      float ep = acc[2*i][j]*alv, rp = acc[2*i][j]*arv;
      #pragma unroll
      for (int off=8; off; off>>=1){ ep += __shfl_xor(ep,off,16); rp += __shfl_xor(rp,off,16); }
      if (c==0){
        int row = row0 + q*4 + j;
        el2[(size_t)i*NN + row] = ep; er2[(size_t)i*NN + row] = rp;
      }
    }
    #pragma unroll
    for (int j=0;j<4;j++){
      int row = row0 + q*4 + j;
      feat16[(size_t)i*NN*16 + (size_t)row*16 + c] = acc[2*i][j];
      resb  [(size_t)i*NN*16 + (size_t)row*16 + c] = acc[2*i+1][j];
    }
  }
}

// ---------- layer-2 dual-graph aggregation (16 cols, H=1) + final mix ----------
__global__ __launch_bounds__(256) void k_agg2D(
    const int* __restrict__ row2, const int* __restrict__ col2,
    const float* __restrict__ feat16, const float* __restrict__ el2,
    const float* __restrict__ er2, const float* __restrict__ resb,
    const float* __restrict__ b2, const float* __restrict__ wsoft,
    float* __restrict__ out)
{
  int t = threadIdx.x;
  int nl = t>>4, j = t&15;
  int n = blockIdx.x*16 + nl;
  int type = (n<NN0)?0:1;
  float o = 0.f;
  #pragma unroll
  for (int i=0;i<2;i++){
    const int* rw = row2 + (size_t)i*(NN+1);
    const int* cl = col2 + (size_t)i*EE;
    const float* f  = feat16 + (size_t)i*NN*16;
    const float* eli= el2 + (size_t)i*NN;
    float ern = er2[(size_t)i*NN + n];
    int beg = rw[n], end = rw[n+1];
    float den = 0.f, acc = 0.f;
    int k = beg;
    for (; k+4<=end; k+=4){
      int s0=cl[k], s1=cl[k+1], s2=cl[k+2], s3=cl[k+3];
      float x0 = __expf(lrelu(eli[s0] + ern));
      float x1 = __expf(lrelu(eli[s1] + ern));
      float x2 = __expf(lrelu(eli[s2] + ern));
      float x3 = __expf(lrelu(eli[s3] + ern));
      float v0 = f[(size_t)s0*16 + j];
      float v1 = f[(size_t)s1*16 + j];
      float v2 = f[(size_t)s2*16 + j];
      float v3 = f[(size_t)s3*16 + j];
      den += (x0+x1) + (x2+x3);
      acc += x0*v0 + x1*v1 + x2*v2 + x3*v3;
    }
    for (; k<end; k++){
      int s = cl[k];
      float x = __expf(lrelu(eli[s] + ern));
      den += x;
      acc = fmaf(x, f[(size_t)s*16 + j], acc);
    }
    float inv = (end>beg) ? 1.0f/den : 0.f;
    float oi = acc*inv + b2[i*16+j] + resb[(size_t)i*NN*16 + (size_t)n*16 + j];
    o += oi * wsoft[type*6 + 4 + i];
  }
  out[(size_t)n*16 + j] = o;
}

extern "C" void kernel_launch(void* const* d_in, const int* in_sizes, int n_in,
                              void* d_out, int out_size, void* d_ws, size_t ws_size,
                              hipStream_t stream)
{
  const float* features0 = (const float*)d_in[0];
  const float* features1 = (const float*)d_in[1];
  const float* fc_w0 = (const float*)d_in[2];
  const float* fc_b0 = (const float*)d_in[3];
  const float* fc_w1 = (const float*)d_in[4];
  const float* fc_b1 = (const float*)d_in[5];
  const float* mix_w = (const float*)d_in[6];
  const float* W0  = (const float*)d_in[7];
  const float* al0 = (const float*)d_in[8];
  const float* ar0 = (const float*)d_in[9];
  const float* b0  = (const float*)d_in[10];
  const float* W1  = (const float*)d_in[11];
  const float* al1 = (const float*)d_in[12];
  const float* ar1 = (const float*)d_in[13];
  const float* b1  = (const float*)d_in[14];
  const float* W2  = (const float*)d_in[15];
  const float* al2 = (const float*)d_in[16];
  const float* ar2 = (const float*)d_in[17];
  const float* b2  = (const float*)d_in[18];
  const float* res2= (const float*)d_in[19];
  const int* src[2] = {(const int*)d_in[20], (const int*)d_in[22]};
  const int* dst[2] = {(const int*)d_in[21], (const int*)d_in[23]};
  (void)in_sizes; (void)n_in; (void)out_size; (void)ws_size;

  char* ws = (char*)d_ws;
  size_t off = 0;
  auto alloc = [&](size_t bytes)->char*{
    char* p = ws + off; off += (bytes + 255) & ~(size_t)255; return p;
  };
  float* wsoft = (float*)alloc(64*4);
  u16*   W0p   = (u16*)  alloc((size_t)2*64*256*2);
  u16*   W1p   = (u16*)  alloc((size_t)2*256*256*2);
  u16*   W2p   = (u16*)  alloc((size_t)256*64*2);
  u16*   Fp    = (u16*)  alloc((size_t)2*128*64*2);
  u16*   Vp    = (u16*)  alloc((size_t)64*16*2);
  int*   row2  = (int*)  alloc((size_t)2*(NN+1)*4);
  int*   col2  = (int*)  alloc((size_t)2*EE*4);
  int*   zeros = (int*)  alloc((size_t)4*NN*4);       // cnt2 + fill2, one memset
  int*   cnt2  = zeros;
  int*   fill2 = zeros + 2*NN;
  int*   bsum  = (int*)alloc((size_t)2*NB_SCAN*4);
  int*   boff  = (int*)alloc((size_t)2*NB_SCAN*4);
  u16*   h0    = (u16*)alloc((size_t)NN*64*2);
  u16*   h1    = (u16*)alloc((size_t)NN*256*2);
  u16*   h2    = (u16*)alloc((size_t)NN*256*2);
  float* elA   = (float*)alloc((size_t)2*NN*4*4);
  float* erA   = (float*)alloc((size_t)2*NN*4*4);
  // region D (51.2 MB): layer-0 aggB -> layer-1 featD -> layer-2 outputs
  size_t featStride = (size_t)NN*256;                 // u16 elements per graph
  size_t off_D = off;
  u16* regionD = (u16*)alloc(2*featStride*2);
  u16* aggB  = regionD;
  u16* featD = regionD;
  float* feat16 = (float*)(ws + off_D);
  float* resb   = feat16 + (size_t)2*NN*16;
  float* el2    = resb   + (size_t)2*NN*16;
  float* er2    = el2    + (size_t)2*NN;

  // 1. prep: mixw + pack all weights + V = [W0*al0 | W0*ar0]
  k_prep<<<100,256,0,stream>>>(mix_w, wsoft, W0, W0p, W1, W1p, W2, res2, W2p,
                               fc_w0, fc_w1, Fp, al0, ar0, Vp);

  // 2. CSR build, both graphs
  hipMemsetAsync(zeros, 0, (size_t)4*NN*4, stream);
  {
    dim3 gE((EE+255)/256, 2), gS(NB_SCAN, 2);
    k_count2 <<<gE,256,0,stream>>>(dst[0], dst[1], cnt2);
    k_scan1  <<<gS,1024,0,stream>>>(cnt2, row2, bsum);
    k_scan2  <<<1,128,0,stream>>>(bsum, boff);
    k_scan3  <<<gS,1024,0,stream>>>(row2, boff);
    k_scatter2<<<gE,256,0,stream>>>(src[0], dst[0], src[1], dst[1], row2, fill2, col2);
  }

  // 3. input projection (MFMA) + layer-0 el/er
  k_inproj_m<<<NGRP,256,0,stream>>>(features0, features1, Fp, fc_b0, fc_b1, h0);
  k_eler0   <<<NGRP,256,0,stream>>>(h0, Vp, elA, erA);

  // 4. layer 0: aggregate h0 (L2-resident), then per-head GEMM + ELU + mix -> h1
  k_agg0 <<<NN/4,256,0,stream>>>(row2, col2, h0, elA, erA, aggB, featStride);
  k_head0<<<NGRP,256,0,stream>>>(aggB, featStride, W0p, b0, wsoft, h1);

  // 5. layer 1: feat = h1 @ W1 (MFMA), fused dual-graph aggregation -> h2
  k_gemm4<256><<<2*NGRP,256,0,stream>>>(h1, W1p, (size_t)256*256, al1, ar1, 256,
                                        featD, featStride, elA, erA, (size_t)NN*4);
  k_aggNF<1><<<NN/4,256,0,stream>>>(row2, col2, featD, featStride, elA, erA, (size_t)NN*4,
                                    h1, b1, wsoft, 1, h2);

  // 6. layer 2 (both graphs fused; outputs alias region D — feat dead here)
  k_gemm2<<<NGRP,256,0,stream>>>(h2, W2p, al2, ar2, feat16, resb, el2, er2);
  k_agg2D<<<NN/16,256,0,stream>>>(row2, col2, feat16, el2, er2, resb, b2, wsoft, (float*)d_out);
}

// Round 8
// 459.541 us; speedup vs baseline: 3.9800x; 1.0139x over previous
//
#include <hip/hip_runtime.h>
#include <hip/hip_bf16.h>

// Problem constants (match reference)
#define NN   50000   // N0+N1
#define NN0  30000
#define EE   400000
#define NB_SCAN ((NN + 1023) / 1024)   // 49
#define NRT   3125                     // row tiles (16 rows each)
#define NGRP  ((NRT + 3) / 4)          // 782 row groups (64 rows)
#define NT0   1875                     // type-0 row tiles (30000/16, exact)

typedef unsigned short u16;
typedef unsigned int   u32;

typedef __attribute__((ext_vector_type(8))) __bf16 bf16x8;
typedef __attribute__((ext_vector_type(4))) float  f32x4;

// ---------- bf16 storage helpers (fp32 math everywhere) ----------
__device__ __forceinline__ float bf2f(u16 u){ return __uint_as_float(((u32)u)<<16); }
__device__ __forceinline__ float lo16(u32 u){ return __uint_as_float(u<<16); }
__device__ __forceinline__ float hi16(u32 u){ return __uint_as_float(u & 0xffff0000u); }
__device__ __forceinline__ u16 f2bf(float f){
  u32 x = __float_as_uint(f);
  x += 0x7fffu + ((x>>16)&1u);      // round-to-nearest-even
  return (u16)(x>>16);
}
__device__ __forceinline__ float elu_f(float x){ return x>0.f ? x : __expf(x)-1.f; }
__device__ __forceinline__ float lrelu(float x){ return x>0.f ? x : 0.2f*x; }
__device__ __forceinline__ bf16x8 ld_frag(const u16* p){
  uint4 v = *(const uint4*)p;
  return __builtin_bit_cast(bf16x8, v);
}
__device__ __forceinline__ bf16x8 cvt8(const float* p){   // 8 f32 -> bf16x8
  float4 u = ((const float4*)p)[0];
  float4 v = ((const float4*)p)[1];
  u32 w0 = (u32)f2bf(u.x) | ((u32)f2bf(u.y)<<16);
  u32 w1 = (u32)f2bf(u.z) | ((u32)f2bf(u.w)<<16);
  u32 w2 = (u32)f2bf(v.x) | ((u32)f2bf(v.y)<<16);
  u32 w3 = (u32)f2bf(v.z) | ((u32)f2bf(v.w)<<16);
  uint4 r{w0,w1,w2,w3};
  return __builtin_bit_cast(bf16x8, r);
}

// ---------- fused prep: mixw softmax + all weight packing + V = [W*al | W*ar] --
__global__ __launch_bounds__(256) void k_prep(
    const float* __restrict__ mix_w, float* __restrict__ wsoft,
    const float* __restrict__ W0, u16* __restrict__ W0p,
    const float* __restrict__ W1, u16* __restrict__ W1p,
    const float* __restrict__ W2, const float* __restrict__ res2, u16* __restrict__ W2p,
    const float* __restrict__ fcw0, const float* __restrict__ fcw1, u16* __restrict__ Fp,
    const float* __restrict__ al0, const float* __restrict__ ar0, u16* __restrict__ Vp)
{
  int t = blockIdx.x*256 + threadIdx.x;
  if (t < 6){
    float a0 = mix_w[t*2+0], a1 = mix_w[t*2+1];
    float mx = fmaxf(a0,a1);
    float e0 = __expf(a0-mx), e1 = __expf(a1-mx);
    wsoft[t*2+0] = e0/(e0+e1); wsoft[t*2+1] = e1/(e0+e1);
  }
  if (t < 4096){                    // W0: per graph 2048 frags, KB=2, NCOL=256
    int gg = t>>11, fi = t&2047;
    int lane = fi&63, kb = (fi>>6)&1, ct = fi>>7;
    int q = lane>>4, c = lane&15;
    const float* src = W0 + (size_t)gg*16384;
    u16* o = W0p + (size_t)gg*16384 + (size_t)fi*8;
    #pragma unroll
    for (int j=0;j<8;j++) o[j] = f2bf(src[(size_t)(kb*32+q*8+j)*256 + ct*16 + c]);
  } else if (t < 20480){            // W1: per graph 8192 frags, KB=8, NCOL=256
    int u = t - 4096;
    int gg = u>>13, fi = u&8191;
    int lane = fi&63, kb = (fi>>6)&7, ct = fi>>9;
    int q = lane>>4, c = lane&15;
    const float* src = W1 + (size_t)gg*65536;
    u16* o = W1p + (size_t)gg*65536 + (size_t)fi*8;
    #pragma unroll
    for (int j=0;j<8;j++) o[j] = f2bf(src[(size_t)(kb*32+q*8+j)*256 + ct*16 + c]);
  } else if (t < 22528){            // W2cat: 2048 frags, KB=8, NCOL=64
    int fi = t - 20480;
    int lane = fi&63, kb = (fi>>6)&7, ct = fi>>9;
    int q = lane>>4, c = lane&15;
    int cl = ct*16 + c;
    int i = cl>>5, which = (cl>>4)&1;
    const float* src = which ? res2 : W2;
    u16* o = W2p + (size_t)fi*8;
    #pragma unroll
    for (int j=0;j<8;j++) o[j] = f2bf(src[(size_t)i*4096 + (size_t)(kb*32+q*8+j)*16 + (cl&15)]);
  } else if (t < 24576){            // fc_w: per type 1024 frags, KB=4, NCOL=64
    int u = t - 22528;
    int tt = u>>10, fi = u&1023;
    int lane = fi&63, kb = (fi>>6)&3, ct = fi>>8;
    int q = lane>>4, c = lane&15;
    const float* src = tt ? fcw1 : fcw0;
    u16* o = Fp + (size_t)tt*8192 + (size_t)fi*8;
    #pragma unroll
    for (int j=0;j<8;j++) o[j] = f2bf(src[(size_t)(kb*32+q*8+j)*64 + ct*16 + c]);
  } else if (t < 25600){            // Vp: 64x16, KB=2; col c: which=c>>3, g=(c>>2)&1, h=c&3
    int u = t - 24576;
    int fi = u>>3, j = u&7;
    int lane = fi&63, kb = fi>>6;
    int q = lane>>4, c = lane&15;
    int k = kb*32 + q*8 + j;
    int which = c>>3, g=(c>>2)&1, h=c&3;
    const float* sel = (which ? ar0 : al0) + (size_t)(g*4+h)*64;
    const float* Wrow = W0 + (size_t)g*16384 + (size_t)k*256 + h*64;
    float s=0.f;
    #pragma unroll 8
    for (int d=0;d<64;d++) s = fmaf(Wrow[d], sel[d], s);
    Vp[(size_t)fi*8 + j] = f2bf(s);
  }
}

// ================= CSR build (both graphs, rebuilt every launch) ===============
__global__ void k_count2(const int* __restrict__ d0, const int* __restrict__ d1,
                         int* __restrict__ cnt2){
  int t = blockIdx.x*256 + threadIdx.x;
  int g = blockIdx.y;
  if (t < EE) atomicAdd(&cnt2[g*NN + (g ? d1[t] : d0[t])], 1);
}

__global__ __launch_bounds__(1024) void k_scan1(const int* __restrict__ cnt2,
                                                int* __restrict__ row2, int* __restrict__ bsum){
  __shared__ int wsum[16];
  int g = blockIdx.y;
  int lane = threadIdx.x & 63, wid = threadIdx.x >> 6;
  int i = blockIdx.x*1024 + threadIdx.x;
  int v = (i < NN) ? cnt2[g*NN + i] : 0;
  int x = v;
  #pragma unroll
  for (int off = 1; off < 64; off <<= 1){
    int y = __shfl_up(x, off, 64);
    if (lane >= off) x += y;
  }
  if (lane == 63) wsum[wid] = x;
  __syncthreads();
  if (wid == 0 && lane < 16){
    int s = wsum[lane];
    #pragma unroll
    for (int off = 1; off < 16; off <<= 1){
      int y = __shfl_up(s, off, 16);
      if (lane >= off) s += y;
    }
    wsum[lane] = s;
  }
  __syncthreads();
  int incl = x + (wid ? wsum[wid-1] : 0);
  if (i < NN) row2[(size_t)g*(NN+1) + i] = incl - v;
  if (threadIdx.x == 1023) bsum[g*NB_SCAN + blockIdx.x] = incl;
}

__global__ __launch_bounds__(128) void k_scan2(const int* __restrict__ bsum, int* __restrict__ boff){
  int g = threadIdx.x >> 6, lane = threadIdx.x & 63;
  int v = (lane < NB_SCAN) ? bsum[g*NB_SCAN + lane] : 0;
  int x = v;
  #pragma unroll
  for (int off = 1; off < 64; off <<= 1){
    int y = __shfl_up(x, off, 64);
    if (lane >= off) x += y;
  }
  if (lane < NB_SCAN) boff[g*NB_SCAN + lane] = x - v;
}

__global__ __launch_bounds__(1024) void k_scan3(int* __restrict__ row2, const int* __restrict__ boff){
  int g = blockIdx.y;
  int i = blockIdx.x*1024 + threadIdx.x;
  if (i < NN) row2[(size_t)g*(NN+1) + i] += boff[g*NB_SCAN + blockIdx.x];
  if (blockIdx.x == 0 && threadIdx.x == 0) row2[(size_t)g*(NN+1) + NN] = EE;
}

// scatter: col2 (u16 src id) + dstOf (u16 dst id) per CSR slot
__global__ void k_scatter2(const int* __restrict__ s0, const int* __restrict__ d0,
                           const int* __restrict__ s1, const int* __restrict__ d1,
                           const int* __restrict__ row2, int* __restrict__ fill2,
                           u16* __restrict__ col2, u16* __restrict__ dstOf){
  int t = blockIdx.x*256 + threadIdx.x;
  int g = blockIdx.y;
  if (t >= EE) return;
  int d = g ? d1[t] : d0[t];
  int s = g ? s1[t] : s0[t];
  int pos = atomicAdd(&fill2[g*NN + d], 1);
  size_t slot = (size_t)g*EE + row2[(size_t)g*(NN+1) + d] + pos;
  col2[slot]  = (u16)s;
  dstOf[slot] = (u16)d;
}

// ---------- alpha precompute (H=4): x[slot][h] = exp(lrelu(el[s][h]+er[d][h])) --
__global__ void k_alpha4(const u16* __restrict__ col2, const u16* __restrict__ dstOf,
                         const float* __restrict__ el, const float* __restrict__ er,
                         size_t elStride, float* __restrict__ xbuf){
  int t = blockIdx.x*256 + threadIdx.x;
  int g = blockIdx.y;
  if (t >= EE) return;
  size_t slot = (size_t)g*EE + t;
  int s = col2[slot], d = dstOf[slot];
  const float* elg = el + (size_t)g*elStride;
  const float* erg = er + (size_t)g*elStride;
  float4 e4 = ((const float4*)elg)[s];
  float4 r4 = ((const float4*)erg)[d];
  float4 x;
  x.x = __expf(lrelu(e4.x + r4.x));
  x.y = __expf(lrelu(e4.y + r4.y));
  x.z = __expf(lrelu(e4.z + r4.z));
  x.w = __expf(lrelu(e4.w + r4.w));
  ((float4*)xbuf)[slot] = x;
}

// ---------- alpha precompute (H=1, layer 2) ----------
__global__ void k_alpha1(const u16* __restrict__ col2, const u16* __restrict__ dstOf,
                         const float* __restrict__ el2, const float* __restrict__ er2,
                         float* __restrict__ xb2){
  int t = blockIdx.x*256 + threadIdx.x;
  int g = blockIdx.y;
  if (t >= EE) return;
  size_t slot = (size_t)g*EE + t;
  int s = col2[slot], d = dstOf[slot];
  xb2[slot] = __expf(lrelu(el2[(size_t)g*NN + s] + er2[(size_t)g*NN + d]));
}

// ---------- input projection (MFMA): h0(N,64) = feat_t @ fc_w_t + fc_b_t -------
__global__ __launch_bounds__(256) void k_inproj_m(
    const float* __restrict__ f0, const float* __restrict__ f1,
    const u16* __restrict__ Fp, const float* __restrict__ fb0, const float* __restrict__ fb1,
    u16* __restrict__ h0)
{
  int wv = threadIdx.x>>6, ln = threadIdx.x&63;
  int ti = blockIdx.x*4 + wv;
  if (ti >= NRT) return;
  int q = ln>>4, c = ln&15;
  int type = (ti < NT0) ? 0 : 1;
  const float* F = type ? f1 : f0;
  int rbase = type ? (ti*16 - NN0) : ti*16;
  const u16* Bg = Fp + (size_t)type*8192;
  const float* bb = type ? fb1 : fb0;
  f32x4 acc[4] = {};
  const float* Ap = F + (size_t)(rbase + c)*128;
  #pragma unroll
  for (int kb=0; kb<4; kb++){
    bf16x8 a = cvt8(Ap + kb*32 + q*8);
    #pragma unroll
    for (int ct=0; ct<4; ct++){
      bf16x8 b = ld_frag(Bg + ((size_t)(ct*4+kb)*64 + ln)*8);
      acc[ct] = __builtin_amdgcn_mfma_f32_16x16x32_bf16(a, b, acc[ct], 0,0,0);
    }
  }
  #pragma unroll
  for (int ct=0; ct<4; ct++){
    float bv = bb[ct*16+c];
    #pragma unroll
    for (int j=0;j<4;j++){
      int row = ti*16 + q*4 + j;
      h0[(size_t)row*64 + ct*16 + c] = f2bf(acc[ct][j] + bv);
    }
  }
}

// ---------- layer-0 el/er: (N,64) @ Vp(64,16) ----------
__global__ __launch_bounds__(256) void k_eler0(
    const u16* __restrict__ h0, const u16* __restrict__ Vp,
    float* __restrict__ elA, float* __restrict__ erA)
{
  int wv = threadIdx.x>>6, ln = threadIdx.x&63;
  int ti = blockIdx.x*4 + wv;
  if (ti >= NRT) return;
  int q = ln>>4, c = ln&15;
  f32x4 acc = {};
  const u16* Ap = h0 + (size_t)(ti*16 + c)*64 + q*8;
  #pragma unroll
  for (int kb=0; kb<2; kb++){
    bf16x8 a = ld_frag(Ap + kb*32);
    bf16x8 b = ld_frag(Vp + ((size_t)(kb*64 + ln))*8);
    acc = __builtin_amdgcn_mfma_f32_16x16x32_bf16(a, b, acc, 0,0,0);
  }
  int which = c>>3, g = (c>>2)&1, h = c&3;
  float* dst = (which ? erA : elA) + (size_t)g*NN*4;
  #pragma unroll
  for (int j=0;j<4;j++){
    int row = ti*16 + q*4 + j;
    dst[row*4 + h] = acc[j];
  }
}

// ---------- layer-0 aggregation: gather h0 (64 cols), precomputed x ----------
__global__ __launch_bounds__(256) void k_agg0(
    const int* __restrict__ row2, const u16* __restrict__ col2,
    const float* __restrict__ xbuf, const u16* __restrict__ h0,
    u16* __restrict__ aggB, size_t aggStride)
{
  int wv = threadIdx.x>>6, ln = threadIdx.x&63;
  int n = blockIdx.x*4 + wv;
  #pragma unroll
  for (int g=0; g<2; g++){
    const int* rw = row2 + (size_t)g*(NN+1);
    const u16* cl = col2 + (size_t)g*EE;
    const float4* xb = (const float4*)xbuf + (size_t)g*EE;
    int beg = rw[n], end = rw[n+1];
    float d0=0.f,d1=0.f,d2=0.f,d3=0.f;
    float a0=0.f,a1=0.f,a2=0.f,a3=0.f;
    int k = beg;
    for (; k+2<=end; k+=2){
      int s0 = cl[k], s1 = cl[k+1];
      float4 x0 = xb[k], x1 = xb[k+1];
      float v0 = bf2f(h0[(size_t)s0*64 + ln]);
      float v1 = bf2f(h0[(size_t)s1*64 + ln]);
      d0 += x0.x+x1.x; d1 += x0.y+x1.y; d2 += x0.z+x1.z; d3 += x0.w+x1.w;
      a0 += x0.x*v0 + x1.x*v1; a1 += x0.y*v0 + x1.y*v1;
      a2 += x0.z*v0 + x1.z*v1; a3 += x0.w*v0 + x1.w*v1;
    }
    for (; k<end; k++){
      int s = cl[k];
      float4 x = xb[k];
      float v = bf2f(h0[(size_t)s*64 + ln]);
      d0+=x.x; d1+=x.y; d2+=x.z; d3+=x.w;
      a0+=x.x*v; a1+=x.y*v; a2+=x.z*v; a3+=x.w*v;
    }
    bool has = (end > beg);
    a0 = has ? a0/d0 : 0.f; a1 = has ? a1/d1 : 0.f;
    a2 = has ? a2/d2 : 0.f; a3 = has ? a3/d3 : 0.f;
    u16* og = aggB + (size_t)g*aggStride + (size_t)n*256 + ln;
    og[0]   = f2bf(a0); og[64]  = f2bf(a1);
    og[128] = f2bf(a2); og[192] = f2bf(a3);
  }
}

// ---------- layer-0 head GEMM: ELU(agg@W0_blockdiag + b) mixed -> h1 ----------
__global__ __launch_bounds__(256) void k_head0(
    const u16* __restrict__ aggB, size_t aggStride,
    const u16* __restrict__ W0p, const float* __restrict__ b0,
    const float* __restrict__ wsoft, u16* __restrict__ h1)
{
  int wv = threadIdx.x>>6, ln = threadIdx.x&63;
  int ti = blockIdx.x*4 + wv;
  if (ti >= NRT) return;
  int q = ln>>4, c = ln&15;
  int type = (ti < NT0) ? 0 : 1;
  float wg0 = wsoft[type*6 + 0];
  float wg1 = wsoft[type*6 + 1];
  for (int h=0; h<4; h++){
    f32x4 acc[2][4] = {};
    #pragma unroll
    for (int g=0; g<2; g++){
      const u16* Ap = aggB + (size_t)g*aggStride + (size_t)(ti*16 + c)*256 + h*64 + q*8;
      const u16* Bg = W0p + (size_t)g*16384;
      #pragma unroll
      for (int kb=0; kb<2; kb++){
        bf16x8 a = ld_frag(Ap + kb*32);
        #pragma unroll
        for (int ct=0; ct<4; ct++){
          int ctg = h*4 + ct;
          bf16x8 b = ld_frag(Bg + ((size_t)(ctg*2 + kb)*64 + ln)*8);
          acc[g][ct] = __builtin_amdgcn_mfma_f32_16x16x32_bf16(a, b, acc[g][ct], 0,0,0);
        }
      }
    }
    #pragma unroll
    for (int ct=0; ct<4; ct++){
      int colg = h*64 + ct*16 + c;
      float bb0 = b0[colg], bb1 = b0[256 + colg];
      #pragma unroll
      for (int j=0;j<4;j++){
        int row = ti*16 + q*4 + j;
        float o = wg0*elu_f(acc[0][ct][j] + bb0) + wg1*elu_f(acc[1][ct][j] + bb1);
        h1[(size_t)row*256 + colg] = f2bf(o);
      }
    }
  }
}

// ---------- MFMA GEMM, 4 row-tiles x 4 col-tiles per wave (layer 1) ------------
template<int K>
__global__ __launch_bounds__(256) void k_gemm4(
    const u16* __restrict__ A,
    const u16* __restrict__ Bp, size_t bpStride,
    const float* __restrict__ al, const float* __restrict__ ar, int alStride,
    u16* __restrict__ feat, size_t featStride,
    float* __restrict__ el, float* __restrict__ er, size_t elStride)
{
  constexpr int KB = K/32;
  int wv = threadIdx.x>>6, ln = threadIdx.x&63;
  int bid = blockIdx.x;
  int g = bid / NGRP, grp = bid % NGRP;
  int split = wv, q = ln>>4, c = ln&15;
  const u16* Bpg = Bp + (size_t)g*bpStride;
  const float* alg = al + (size_t)g*alStride;
  const float* arg = ar + (size_t)g*alStride;
  u16* featg = feat + (size_t)g*featStride;
  float* elg = el + (size_t)g*elStride;
  float* erg = er + (size_t)g*elStride;

  f32x4 acc[4][4] = {};
  int  tbase = grp*4;
  bool valid[4];
  const u16* Ap[4];
  #pragma unroll
  for (int rt=0; rt<4; rt++){
    int ti = tbase + rt;
    valid[rt] = (ti < NRT);
    if (!valid[rt]) ti = NRT-1;
    Ap[rt] = A + (size_t)(ti*16 + c)*K + q*8;
  }
  const u16* Bbase = Bpg + ((size_t)(split*4)*KB*64 + ln)*8;

  #pragma unroll 2
  for (int kb=0; kb<KB; kb++){
    bf16x8 b[4], a[4];
    #pragma unroll
    for (int ct=0; ct<4; ct++) b[ct] = ld_frag(Bbase + (size_t)(ct*KB + kb)*64*8);
    #pragma unroll
    for (int rt=0; rt<4; rt++) a[rt] = ld_frag(Ap[rt] + kb*32);
    #pragma unroll
    for (int rt=0; rt<4; rt++)
      #pragma unroll
      for (int ct=0; ct<4; ct++)
        acc[rt][ct] = __builtin_amdgcn_mfma_f32_16x16x32_bf16(a[rt], b[ct], acc[rt][ct], 0,0,0);
  }

  float alv[4], arv[4];
  #pragma unroll
  for (int ct=0;ct<4;ct++){
    int cg = (split*4+ct)*16 + c;
    alv[ct] = alg[cg]; arv[ct] = arg[cg];
  }
  #pragma unroll
  for (int rt=0; rt<4; rt++){
    if (!valid[rt]) continue;
    int row0 = (tbase+rt)*16;
    #pragma unroll
    for (int j=0;j<4;j++){
      float ep=0.f, rp=0.f;
      #pragma unroll
      for (int ct=0;ct<4;ct++){ ep += acc[rt][ct][j]*alv[ct]; rp += acc[rt][ct][j]*arv[ct]; }
      #pragma unroll
      for (int off=8; off; off>>=1){ ep += __shfl_xor(ep,off,16); rp += __shfl_xor(rp,off,16); }
      int row = row0 + q*4 + j;
      if (c==0){ elg[row*4+split]=ep; erg[row*4+split]=rp; }
      #pragma unroll
      for (int ct=0;ct<4;ct++)
        featg[(size_t)row*256 + (split*4+ct)*16 + c] = f2bf(acc[rt][ct][j]);
    }
  }
}

// ---------- fused dual-graph gather aggregation (256 cols, H=4), layer 1 -------
// x precomputed; lane h = ln>>4 reads xb[k*4+h]
template<int RES>
__global__ __launch_bounds__(256) void k_aggNF(
    const int* __restrict__ row2, const u16* __restrict__ col2,
    const float* __restrict__ xbuf,
    const u16* __restrict__ feat, size_t featStride,
    const u16* __restrict__ hres, const float* __restrict__ bias,
    const float* __restrict__ wsoft, int l,
    u16* __restrict__ hout)
{
  int wv = threadIdx.x>>6, ln = threadIdx.x&63;
  int n = blockIdx.x*4 + wv;
  int h = ln>>4;
  int type = (n<NN0)?0:1;
  float rx=0.f, ry=0.f, rz=0.f, rw_=0.f;
  if (RES){
    uint2 r = ((const uint2*)hres)[(size_t)n*64 + ln];
    rx=lo16(r.x); ry=hi16(r.x); rz=lo16(r.y); rw_=hi16(r.y);
  }
  float o0=0.f,o1=0.f,o2=0.f,o3=0.f;
  #pragma unroll
  for (int g=0; g<2; g++){
    const int* rw = row2 + (size_t)g*(NN+1);
    const u16* cl = col2 + (size_t)g*EE;
    const float* xb = xbuf + (size_t)g*EE*4;
    const uint2* fp = (const uint2*)(feat + (size_t)g*featStride);
    int beg = rw[n], end = rw[n+1];
    float den = 0.f;
    float a0=0.f,a1=0.f,a2=0.f,a3=0.f;
    int k = beg;
    for (; k+4<=end; k+=4){
      int s0=cl[k], s1=cl[k+1], s2=cl[k+2], s3=cl[k+3];
      float x0 = xb[(size_t)k*4 + h];
      float x1 = xb[(size_t)(k+1)*4 + h];
      float x2 = xb[(size_t)(k+2)*4 + h];
      float x3 = xb[(size_t)(k+3)*4 + h];
      uint2 f0 = fp[(size_t)s0*64 + ln];
      uint2 f1 = fp[(size_t)s1*64 + ln];
      uint2 f2 = fp[(size_t)s2*64 + ln];
      uint2 f3 = fp[(size_t)s3*64 + ln];
      den += (x0+x1) + (x2+x3);
      a0 += x0*lo16(f0.x) + x1*lo16(f1.x) + x2*lo16(f2.x) + x3*lo16(f3.x);
      a1 += x0*hi16(f0.x) + x1*hi16(f1.x) + x2*hi16(f2.x) + x3*hi16(f3.x);
      a2 += x0*lo16(f0.y) + x1*lo16(f1.y) + x2*lo16(f2.y) + x3*lo16(f3.y);
      a3 += x0*hi16(f0.y) + x1*hi16(f1.y) + x2*hi16(f2.y) + x3*hi16(f3.y);
    }
    for (; k<end; k++){
      int s = cl[k];
      float x = xb[(size_t)k*4 + h];
      uint2 f = fp[(size_t)s*64 + ln];
      den += x;
      a0 += x*lo16(f.x); a1 += x*hi16(f.x); a2 += x*lo16(f.y); a3 += x*hi16(f.y);
    }
    float inv = (end>beg) ? 1.0f/den : 0.f;
    float4 bv = ((const float4*)(bias + g*256))[ln];
    a0 = a0*inv + bv.x; a1 = a1*inv + bv.y; a2 = a2*inv + bv.z; a3 = a3*inv + bv.w;
    if (RES){ a0 += rx; a1 += ry; a2 += rz; a3 += rw_; }
    float w = wsoft[type*6 + l*2 + g];
    o0 += w*elu_f(a0); o1 += w*elu_f(a1); o2 += w*elu_f(a2); o3 += w*elu_f(a3);
  }
  uint2 o;
  o.x = (u32)f2bf(o0) | ((u32)f2bf(o1)<<16);
  o.y = (u32)f2bf(o2) | ((u32)f2bf(o3)<<16);
  ((uint2*)hout)[(size_t)n*64 + ln] = o;
}

// ---------- layer-2 MFMA: A(N,256) @ [W2_0|res2_0|W2_1|res2_1](256,64) ----------
__global__ __launch_bounds__(256) void k_gemm2(
    const u16* __restrict__ A, const u16* __restrict__ Bp,
    const float* __restrict__ al2, const float* __restrict__ ar2,
    float* __restrict__ feat16, float* __restrict__ resb,
    float* __restrict__ el2, float* __restrict__ er2)
{
  int wv = threadIdx.x>>6, ln = threadIdx.x&63;
  int wt = blockIdx.x*4 + wv;
  if (wt >= NRT) return;
  int row0 = wt*16;
  int q = ln>>4, c = ln&15;
  f32x4 acc[4] = {};
  const u16* Ap = A + (size_t)(row0 + c)*256 + q*8;
  #pragma unroll
  for (int kb=0; kb<8; kb++){
    bf16x8 a = ld_frag(Ap + kb*32);
    #pragma unroll
    for (int t=0;t<4;t++){
      bf16x8 b = ld_frag(Bp + ((size_t)(t*8 + kb)*64 + ln)*8);
      acc[t] = __builtin_amdgcn_mfma_f32_16x16x32_bf16(a, b, acc[t], 0,0,0);
    }
  }
  #pragma unroll
  for (int i=0;i<2;i++){
    float alv = al2[i*16+c], arv = ar2[i*16+c];
    #pragma unroll
    for (int j=0;j<4;j++){
      float ep = acc[2*i][j]*alv, rp = acc[2*i][j]*arv;
      #pragma unroll
      for (int off=8; off; off>>=1){ ep += __shfl_xor(ep,off,16); rp += __shfl_xor(rp,off,16); }
      if (c==0){
        int row = row0 + q*4 + j;
        el2[(size_t)i*NN + row] = ep; er2[(size_t)i*NN + row] = rp;
      }
    }
    #pragma unroll
    for (int j=0;j<4;j++){
      int row = row0 + q*4 + j;
      feat16[(size_t)i*NN*16 + (size_t)row*16 + c] = acc[2*i][j];
      resb  [(size_t)i*NN*16 + (size_t)row*16 + c] = acc[2*i+1][j];
    }
  }
}

// ---------- layer-2 dual-graph aggregation (16 cols, H=1) + final mix ----------
__global__ __launch_bounds__(256) void k_agg2D(
    const int* __restrict__ row2, const u16* __restrict__ col2,
    const float* __restrict__ xb2,
    const float* __restrict__ feat16, const float* __restrict__ resb,
    const float* __restrict__ b2, const float* __restrict__ wsoft,
    float* __restrict__ out)
{
  int t = threadIdx.x;
  int nl = t>>4, j = t&15;
  int n = blockIdx.x*16 + nl;
  int type = (n<NN0)?0:1;
  float o = 0.f;
  #pragma unroll
  for (int i=0;i<2;i++){
    const int* rw = row2 + (size_t)i*(NN+1);
    const u16* cl = col2 + (size_t)i*EE;
    const float* xb = xb2 + (size_t)i*EE;
    const float* f  = feat16 + (size_t)i*NN*16;
    int beg = rw[n], end = rw[n+1];
    float den = 0.f, acc = 0.f;
    int k = beg;
    for (; k+4<=end; k+=4){
      int s0=cl[k], s1=cl[k+1], s2=cl[k+2], s3=cl[k+3];
      float x0 = xb[k], x1 = xb[k+1], x2 = xb[k+2], x3 = xb[k+3];
      float v0 = f[(size_t)s0*16 + j];
      float v1 = f[(size_t)s1*16 + j];
      float v2 = f[(size_t)s2*16 + j];
      float v3 = f[(size_t)s3*16 + j];
      den += (x0+x1) + (x2+x3);
      acc += x0*v0 + x1*v1 + x2*v2 + x3*v3;
    }
    for (; k<end; k++){
      int s = cl[k];
      float x = xb[k];
      den += x;
      acc = fmaf(x, f[(size_t)s*16 + j], acc);
    }
    float inv = (end>beg) ? 1.0f/den : 0.f;
    float oi = acc*inv + b2[i*16+j] + resb[(size_t)i*NN*16 + (size_t)n*16 + j];
    o += oi * wsoft[type*6 + 4 + i];
  }
  out[(size_t)n*16 + j] = o;
}

extern "C" void kernel_launch(void* const* d_in, const int* in_sizes, int n_in,
                              void* d_out, int out_size, void* d_ws, size_t ws_size,
                              hipStream_t stream)
{
  const float* features0 = (const float*)d_in[0];
  const float* features1 = (const float*)d_in[1];
  const float* fc_w0 = (const float*)d_in[2];
  const float* fc_b0 = (const float*)d_in[3];
  const float* fc_w1 = (const float*)d_in[4];
  const float* fc_b1 = (const float*)d_in[5];
  const float* mix_w = (const float*)d_in[6];
  const float* W0  = (const float*)d_in[7];
  const float* al0 = (const float*)d_in[8];
  const float* ar0 = (const float*)d_in[9];
  const float* b0  = (const float*)d_in[10];
  const float* W1  = (const float*)d_in[11];
  const float* al1 = (const float*)d_in[12];
  const float* ar1 = (const float*)d_in[13];
  const float* b1  = (const float*)d_in[14];
  const float* W2  = (const float*)d_in[15];
  const float* al2 = (const float*)d_in[16];
  const float* ar2 = (const float*)d_in[17];
  const float* b2  = (const float*)d_in[18];
  const float* res2= (const float*)d_in[19];
  const int* src[2] = {(const int*)d_in[20], (const int*)d_in[22]};
  const int* dst[2] = {(const int*)d_in[21], (const int*)d_in[23]};
  (void)in_sizes; (void)n_in; (void)out_size; (void)ws_size;

  char* ws = (char*)d_ws;
  size_t off = 0;
  auto alloc = [&](size_t bytes)->char*{
    char* p = ws + off; off += (bytes + 255) & ~(size_t)255; return p;
  };
  float* wsoft = (float*)alloc(64*4);
  u16*   W0p   = (u16*)  alloc((size_t)2*64*256*2);
  u16*   W1p   = (u16*)  alloc((size_t)2*256*256*2);
  u16*   W2p   = (u16*)  alloc((size_t)256*64*2);
  u16*   Fp    = (u16*)  alloc((size_t)2*128*64*2);
  u16*   Vp    = (u16*)  alloc((size_t)64*16*2);
  int*   row2  = (int*)  alloc((size_t)2*(NN+1)*4);
  u16*   col2  = (u16*)  alloc((size_t)2*EE*2);
  u16*   dstOf = (u16*)  alloc((size_t)2*EE*2);
  int*   zeros = (int*)  alloc((size_t)4*NN*4);       // cnt2 + fill2, one memset
  int*   cnt2  = zeros;
  int*   fill2 = zeros + 2*NN;
  int*   bsum  = (int*)alloc((size_t)2*NB_SCAN*4);
  int*   boff  = (int*)alloc((size_t)2*NB_SCAN*4);
  u16*   h0    = (u16*)alloc((size_t)NN*64*2);
  u16*   h1    = (u16*)alloc((size_t)NN*256*2);
  u16*   h2    = (u16*)alloc((size_t)NN*256*2);
  float* elA   = (float*)alloc((size_t)2*NN*4*4);
  float* erA   = (float*)alloc((size_t)2*NN*4*4);
  float* xbuf  = (float*)alloc((size_t)2*EE*4*4);     // 12.8 MB, reused L0/L1/L2
  // region D (51.2 MB): layer-0 aggB -> layer-1 featD -> layer-2 outputs
  size_t featStride = (size_t)NN*256;                 // u16 elements per graph
  size_t off_D = off;
  u16* regionD = (u16*)alloc(2*featStride*2);
  u16* aggB  = regionD;
  u16* featD = regionD;
  float* feat16 = (float*)(ws + off_D);
  float* resb   = feat16 + (size_t)2*NN*16;
  float* el2    = resb   + (size_t)2*NN*16;
  float* er2    = el2    + (size_t)2*NN;

  // 1. prep: mixw + pack all weights + V = [W0*al0 | W0*ar0]
  k_prep<<<100,256,0,stream>>>(mix_w, wsoft, W0, W0p, W1, W1p, W2, res2, W2p,
                               fc_w0, fc_w1, Fp, al0, ar0, Vp);

  // 2. CSR build, both graphs
  hipMemsetAsync(zeros, 0, (size_t)4*NN*4, stream);
  {
    dim3 gE((EE+255)/256, 2), gS(NB_SCAN, 2);
    k_count2 <<<gE,256,0,stream>>>(dst[0], dst[1], cnt2);
    k_scan1  <<<gS,1024,0,stream>>>(cnt2, row2, bsum);
    k_scan2  <<<1,128,0,stream>>>(bsum, boff);
    k_scan3  <<<gS,1024,0,stream>>>(row2, boff);
    k_scatter2<<<gE,256,0,stream>>>(src[0], dst[0], src[1], dst[1], row2, fill2, col2, dstOf);
  }

  // 3. input projection (MFMA) + layer-0 el/er
  k_inproj_m<<<NGRP,256,0,stream>>>(features0, features1, Fp, fc_b0, fc_b1, h0);
  k_eler0   <<<NGRP,256,0,stream>>>(h0, Vp, elA, erA);

  dim3 gE((EE+255)/256, 2);

  // 4. layer 0: alpha precompute, aggregate h0, per-head GEMM + ELU + mix -> h1
  k_alpha4<<<gE,256,0,stream>>>(col2, dstOf, elA, erA, (size_t)NN*4, xbuf);
  k_agg0 <<<NN/4,256,0,stream>>>(row2, col2, xbuf, h0, aggB, featStride);
  k_head0<<<NGRP,256,0,stream>>>(aggB, featStride, W0p, b0, wsoft, h1);

  // 5. layer 1: feat = h1 @ W1 (MFMA), alpha, fused dual-graph aggregation -> h2
  k_gemm4<256><<<2*NGRP,256,0,stream>>>(h1, W1p, (size_t)256*256, al1, ar1, 256,
                                        featD, featStride, elA, erA, (size_t)NN*4);
  k_alpha4<<<gE,256,0,stream>>>(col2, dstOf, elA, erA, (size_t)NN*4, xbuf);
  k_aggNF<1><<<NN/4,256,0,stream>>>(row2, col2, xbuf, featD, featStride,
                                    h1, b1, wsoft, 1, h2);

  // 6. layer 2 (both graphs fused; outputs alias region D — feat dead here)
  k_gemm2<<<NGRP,256,0,stream>>>(h2, W2p, al2, ar2, feat16, resb, el2, er2);
  k_alpha1<<<gE,256,0,stream>>>(col2, dstOf, el2, er2, xbuf);
  k_agg2D<<<NN/16,256,0,stream>>>(row2, col2, xbuf, feat16, resb, b2, wsoft, (float*)d_out);
}